// Round 8
// baseline (265.816 us; speedup 1.0000x reference)
//
#include <hip/hip_runtime.h>

// MHR_76965813945133: x->QKV proj -> 3x causal MHA (Q<-ctx, K/V fixed) -> out proj.
// B=2, S=2048, D=1024, NH=16, HD=64. bf16 MFMA compute, fp32 accum.
// R18 = R17 resubmitted (container infra failure, same signature as R14's; source
//      re-audited: barriers convergent, scratch in-bounds/aligned, no fault path).
//      Split-KV across wave halves: R15 shell (q-tile 128, grid (32,16) mirror,
//      paired staging, 1 barrier/pair, 2 blocks/CU) + waves 0-3/4-7 share the same
//      128 q rows but split KV tiles (A=even, B=odd) -> each tile read by 4 waves
//      not 8 -> LDS reads halve. Sum-only softmax => merge = od+=partner via Ks
//      scratch once per rep. launch_bounds(512,4); watch WRITE_SIZE for spill.

#define D_MODEL 1024
#define NHEADS  16
#define HD      64
#define SEQ     2048
#define BATCH   2
#define NROWS   (BATCH*SEQ)   // 4096
#define NQKV    (3*D_MODEL)   // 3072
#define SCL2F   0.1803368801111601f      // 0.125 * log2(e)
#define MASK2   (-14426.950408889634f)   // -10000 * log2(e)

typedef __bf16 bf16x8 __attribute__((ext_vector_type(8)));
typedef float  f32x4  __attribute__((ext_vector_type(4)));
typedef unsigned short us8 __attribute__((ext_vector_type(8)));
typedef unsigned short us4 __attribute__((ext_vector_type(4)));
typedef short  s16x4  __attribute__((ext_vector_type(4)));

__device__ __forceinline__ unsigned short f2bf(float f) {
  unsigned int u = __float_as_uint(f);
  u = (u + 0x7fffu + ((u >> 16) & 1u)) >> 16;   // RNE
  return (unsigned short)u;
}

union Pack8 { us8 v; unsigned short e[8]; };
union Pack4 { us4 v; unsigned short e[4]; };

__device__ __forceinline__ us8 cvt8(const float4 &a, const float4 &b) {
  Pack8 p;
  p.e[0]=f2bf(a.x); p.e[1]=f2bf(a.y); p.e[2]=f2bf(a.z); p.e[3]=f2bf(a.w);
  p.e[4]=f2bf(b.x); p.e[5]=f2bf(b.y); p.e[6]=f2bf(b.z); p.e[7]=f2bf(b.w);
  return p.v;
}

__device__ __forceinline__ void gl_lds16(const unsigned short* g, unsigned short* l) {
  __builtin_amdgcn_global_load_lds(
      (const __attribute__((address_space(1))) unsigned int*)g,
      (__attribute__((address_space(3))) unsigned int*)l, 16, 0, 0);
}

// ---------------- fp32 -> bf16 pre-convert (x, Wqkv_w, out_w) --------------------
#define CVT_N1 (NROWS*D_MODEL)    // 4194304
#define CVT_N2 (NQKV*D_MODEL)     // 3145728
#define CVT_N3 (D_MODEL*D_MODEL)  // 1048576

__global__ __launch_bounds__(256) void cvt_all(
    const float* __restrict__ x, const float* __restrict__ wq,
    const float* __restrict__ ow,
    unsigned short* __restrict__ xb, unsigned short* __restrict__ wqb,
    unsigned short* __restrict__ owb)
{
  size_t i = ((size_t)blockIdx.x * 256 + threadIdx.x) * 8;
  const float* src; unsigned short* dst; size_t off;
  if (i < CVT_N1)                { src = x;  dst = xb;  off = i; }
  else if (i < CVT_N1 + CVT_N2)  { src = wq; dst = wqb; off = i - CVT_N1; }
  else                           { src = ow; dst = owb; off = i - CVT_N1 - CVT_N2; }
  float4 a = *(const float4*)(src + off);
  float4 b = *(const float4*)(src + off + 4);
  *(us8*)(dst + off) = cvt8(a, b);
}

// ---------------- QKV GEMM: 128x128x64 tiles, async staging, XOR swizzle ---------
__global__ __launch_bounds__(256) void qkv_gemm(
    const unsigned short* __restrict__ xb, const unsigned short* __restrict__ wqb,
    const float* __restrict__ bias,
    unsigned short* __restrict__ q, unsigned short* __restrict__ k,
    unsigned short* __restrict__ vT)
{
  __shared__ __align__(16) unsigned short As[128*64];
  __shared__ __align__(16) unsigned short Bs[128*64];
  const int tid = threadIdx.x;
  const int m0 = blockIdx.y * 128, n0 = blockIdx.x * 128;
  const int wave = tid >> 6, lane = tid & 63;
  const int wm = (wave >> 1) * 64, wn = (wave & 1) * 64;
  const int lrow = lane & 15, quad = lane >> 4;

  const int dr = lane >> 3;          // row within 8-row chunk
  const int pg = lane & 7;           // physical 16B slot within row
  const int sg = (pg ^ dr) * 8;      // swizzled source column (elems)
  const unsigned short* gA[4]; const unsigned short* gB[4];
  unsigned short *lA[4], *lB[4];
  #pragma unroll
  for (int i = 0; i < 4; i++) {
    int c = wave*4 + i;
    gA[i] = xb  + (size_t)(m0 + c*8 + dr) * D_MODEL + sg;
    gB[i] = wqb + (size_t)(n0 + c*8 + dr) * D_MODEL + sg;
    lA[i] = &As[c*512];
    lB[i] = &Bs[c*512];
  }
  const int px0 = (quad ^ (lrow & 7)) * 8;
  const int px1 = ((quad + 4) ^ (lrow & 7)) * 8;

  f32x4 acc[4][4];
  #pragma unroll
  for (int i = 0; i < 4; i++)
    #pragma unroll
    for (int j = 0; j < 4; j++) acc[i][j] = (f32x4){0.f,0.f,0.f,0.f};

  for (int k0 = 0; k0 < D_MODEL; k0 += 64) {
    __syncthreads();
    #pragma unroll
    for (int i = 0; i < 4; i++) { gl_lds16(gA[i] + k0, lA[i]); gl_lds16(gB[i] + k0, lB[i]); }
    __syncthreads();
    bf16x8 af[4][2], bfr[4][2];
    #pragma unroll
    for (int mf = 0; mf < 4; mf++) {
      int row = wm + mf*16 + lrow;
      af[mf][0] = *(const bf16x8*)&As[row*64 + px0];
      af[mf][1] = *(const bf16x8*)&As[row*64 + px1];
    }
    #pragma unroll
    for (int nb = 0; nb < 4; nb++) {
      int row = wn + nb*16 + lrow;
      bfr[nb][0] = *(const bf16x8*)&Bs[row*64 + px0];
      bfr[nb][1] = *(const bf16x8*)&Bs[row*64 + px1];
    }
    #pragma unroll
    for (int h = 0; h < 2; h++)
      #pragma unroll
      for (int mf = 0; mf < 4; mf++)
        #pragma unroll
        for (int nb = 0; nb < 4; nb++)
          acc[mf][nb] = __builtin_amdgcn_mfma_f32_16x16x32_bf16(af[mf][h], bfr[nb][h], acc[mf][nb], 0, 0, 0);
  }

  #pragma unroll
  for (int mf = 0; mf < 4; mf++) {
    #pragma unroll
    for (int nb = 0; nb < 4; nb++) {
      int n = n0 + wn + nb*16 + lrow;
      int which = n >> 10;
      int h  = (n >> 6) & 15;
      int hd = n & 63;
      int mb = m0 + wm + mf*16 + quad*4;
      int b  = mb >> 11;
      int s  = mb & 2047;
      float bi = bias[n];
      if (which == 2) {
        Pack4 p4;
        #pragma unroll
        for (int r = 0; r < 4; r++) p4.e[r] = f2bf(acc[mf][nb][r] + bi);
        *(us4*)&vT[((size_t)((b*NHEADS + h)*HD + hd))*SEQ + s] = p4.v;
      } else {
        unsigned short* dst = (which == 0) ? q : k;
        float scl = (which == 0) ? SCL2F : 1.0f;
        #pragma unroll
        for (int r = 0; r < 4; r++)
          dst[(size_t)((b*NHEADS + h)*SEQ + s + r)*HD + hd] = f2bf((acc[mf][nb][r] + bi) * scl);
      }
    }
  }
}

// ---------------- fused 3-rep causal flash attention ------------------------------
// R18: 512-thr blocks (8 waves), q-tile 128. Waves 0-3 / 4-7 own the SAME 128 q
// rows (32/wave, dual-qgi); group A (w<4) computes even tiles, group B (w>=4) odd
// tiles of each staged pair. Per-rep merge (od/ls add) via Ks scratch. Grid (32,16)
// mirror-balanced, 2 blocks/CU. 4K+4V buffers, 1 barrier/pair, 2-pair prefetch.
#define LDQ 72   // 144B rows: b128 groups (lrow+quad)%8 -> bank-uniform (R9 errata)

__global__ __launch_bounds__(512, 4) void attn3(
    const unsigned short* __restrict__ qg,
    const unsigned short* __restrict__ kg,
    const unsigned short* __restrict__ vTg,
    unsigned short* __restrict__ ctx)
{
  __shared__ __align__(16) unsigned short Ks[4][64*LDQ];
  __shared__ __align__(16) unsigned short Vs[4][64*LDQ];   // Vs[d][s]; [0..1] = Q-chain
  unsigned short* QC = &Vs[0][0];                          // 128 rows x LDQ
  float* scr = (float*)&Ks[0][0];                          // merge scratch (36,864B)

  const int tid  = threadIdx.x;
  const int w    = tid >> 6, lane = tid & 63;              // w = 0..7
  const int lrow = lane & 15, quad = lane >> 4;
  const int wq = w & 3;                            // q-row group (shared by w, w+4)
  const int hf = w >> 2;                           // tile-half: 0=even, 1=odd
  const int bh = blockIdx.x;
  const int yy = blockIdx.y;
  const int base = (blockIdx.x + yy) & 7;          // 0..7 (mirror permutation)
  const int qt = (yy < 8) ? base : (15 - base);
  const unsigned short* qbase = qg  + (size_t)bh * SEQ * HD;
  const unsigned short* kbase = kg  + (size_t)bh * SEQ * HD;
  const unsigned short* vbase = vTg + (size_t)bh * HD * SEQ;
  unsigned short* cbase = ctx + (size_t)bh * SEQ * HD;

  const int srow = tid >> 3;                       // 64x64 staging: 8 thr/row
  const int sco  = (tid & 7) * 8;                  // one uint4 per thread per tile
  const int qrow = tid >> 2, qc0 = (tid & 3) * 16; // 128-row Q map (2 uint4/thr)

  // stage Q tile (rows qt*128..+127, pre-scaled) into QC
  {
    const unsigned short* src = qbase + (size_t)(qt*128 + qrow)*HD + qc0;
    *(uint4*)&QC[qrow*LDQ + qc0]     = *(const uint4*)src;
    *(uint4*)&QC[qrow*LDQ + qc0 + 8] = *(const uint4*)(src + 8);
  }
  __syncthreads();

  // Q as K=32 B-operand frags: B[k=d=quad*8+j][n=q=lane&15]; 32 q-rows per wave-pair
  bf16x8 qb[2][2];
  #pragma unroll
  for (int qgi = 0; qgi < 2; qgi++) {
    qb[qgi][0] = *(const bf16x8*)&QC[(wq*32 + qgi*16 + lrow)*LDQ + quad*8];
    qb[qgi][1] = *(const bf16x8*)&QC[(wq*32 + qgi*16 + lrow)*LDQ + 32 + quad*8];
  }
  __syncthreads();   // qb reads done before first stores overwrite Vs

  const int qwbase = qt*128 + wq*32;  // this wave's lowest q row
  const int npair = qt + 1;           // tile pairs (tiles 2t, 2t+1); last = 2qt+1

  for (int rep = 0; rep < 3; ++rep) {
    f32x4 od[2][4];
    #pragma unroll
    for (int qgi = 0; qgi < 2; qgi++)
      #pragma unroll
      for (int df = 0; df < 4; df++) od[qgi][df] = (f32x4){0.f,0.f,0.f,0.f};
    float ls[2] = {0.f, 0.f};

    // prefetch pair 0 (tiles 0,1): 2 uint4 K + 2 uint4 V per thread
    uint4 ka, kb, va, vb;
    {
      const unsigned short* ks = kbase + (size_t)srow*HD + sco;
      ka = *(const uint4*)ks;  kb = *(const uint4*)(ks + 64*HD);
      const unsigned short* vs = vbase + (size_t)srow*SEQ + sco;
      va = *(const uint4*)vs;  vb = *(const uint4*)(vs + 64);
    }

    for (int t = 0; t < npair; ++t) {
      const int pb = (t & 1) * 2;    // buffer pair base {pb, pb+1}
      *(uint4*)&Ks[pb][srow*LDQ + sco]   = ka;
      *(uint4*)&Ks[pb+1][srow*LDQ + sco] = kb;
      *(uint4*)&Vs[pb][srow*LDQ + sco]   = va;
      *(uint4*)&Vs[pb+1][srow*LDQ + sco] = vb;
      if (t + 1 < npair) {   // prefetch next pair (tiles 2t+2, 2t+3)
        const unsigned short* ks = kbase + (size_t)((2*t+2)*64 + srow)*HD + sco;
        ka = *(const uint4*)ks;  kb = *(const uint4*)(ks + 64*HD);
        const unsigned short* vs = vbase + (size_t)srow*SEQ + (2*t+2)*64 + sco;
        va = *(const uint4*)vs;  vb = *(const uint4*)(vs + 64);
      }
      __syncthreads();   // ONE barrier per pair (2 tiles)

      // this wave's single tile of the pair
      const int bb = pb + hf;
      const int sbase = (2*t + hf) * 64;
      if (sbase > qwbase + 31) continue;   // wave fully masked for this tile
      // scores: S^T = K * Q^T (K=32), both qgi share the K frags
      f32x4 sc[2][4];
      __builtin_amdgcn_s_setprio(1);
      #pragma unroll
      for (int sf = 0; sf < 4; sf++) {
        bf16x8 a0 = *(const bf16x8*)&Ks[bb][(sf*16 + lrow)*LDQ + quad*8];
        bf16x8 a1 = *(const bf16x8*)&Ks[bb][(sf*16 + lrow)*LDQ + 32 + quad*8];
        f32x4 z0 = (f32x4){0.f,0.f,0.f,0.f}, z1 = (f32x4){0.f,0.f,0.f,0.f};
        z0 = __builtin_amdgcn_mfma_f32_16x16x32_bf16(a0, qb[0][0], z0, 0, 0, 0);
        z1 = __builtin_amdgcn_mfma_f32_16x16x32_bf16(a0, qb[1][0], z1, 0, 0, 0);
        z0 = __builtin_amdgcn_mfma_f32_16x16x32_bf16(a1, qb[0][1], z0, 0, 0, 0);
        z1 = __builtin_amdgcn_mfma_f32_16x16x32_bf16(a1, qb[1][1], z1, 0, 0, 0);
        sc[0][sf] = z0; sc[1][sf] = z1;
      }
      __builtin_amdgcn_s_setprio(0);
      if (sbase + 63 > qwbase) {   // element mask (diag-adjacent tiles only)
        #pragma unroll
        for (int qgi = 0; qgi < 2; qgi++) {
          int ql = qwbase + qgi*16 + lrow;
          #pragma unroll
          for (int sf = 0; sf < 4; sf++)
            #pragma unroll
            for (int r = 0; r < 4; r++)
              if (sbase + sf*16 + quad*4 + r > ql) sc[qgi][sf][r] += MASK2;
        }
      }
      // p = exp2(s); P lands directly in K=16 B-layout
      s16x4 pf[2][4];
      #pragma unroll
      for (int qgi = 0; qgi < 2; qgi++) {
        float lp = 0.f;
        #pragma unroll
        for (int sf = 0; sf < 4; sf++) {
          Pack4 pk;
          #pragma unroll
          for (int r = 0; r < 4; r++) {
            float pe = __builtin_amdgcn_exp2f(sc[qgi][sf][r]);
            lp += pe;
            pk.e[r] = __builtin_bit_cast(unsigned short, (__bf16)pe);
          }
          pf[qgi][sf] = __builtin_bit_cast(s16x4, pk.v);
        }
        ls[qgi] += lp;
      }
      // PV: O^T += V^T * P^T (K=16), both qgi share the V frags
      __builtin_amdgcn_s_setprio(1);
      #pragma unroll
      for (int df = 0; df < 4; df++) {
        s16x4 v0 = *(const s16x4*)&Vs[bb][(df*16 + lrow)*LDQ +  0 + quad*4];
        s16x4 v1 = *(const s16x4*)&Vs[bb][(df*16 + lrow)*LDQ + 16 + quad*4];
        s16x4 v2 = *(const s16x4*)&Vs[bb][(df*16 + lrow)*LDQ + 32 + quad*4];
        s16x4 v3 = *(const s16x4*)&Vs[bb][(df*16 + lrow)*LDQ + 48 + quad*4];
        od[0][df] = __builtin_amdgcn_mfma_f32_16x16x16bf16_1k(v0, pf[0][0], od[0][df], 0, 0, 0);
        od[1][df] = __builtin_amdgcn_mfma_f32_16x16x16bf16_1k(v0, pf[1][0], od[1][df], 0, 0, 0);
        od[0][df] = __builtin_amdgcn_mfma_f32_16x16x16bf16_1k(v1, pf[0][1], od[0][df], 0, 0, 0);
        od[1][df] = __builtin_amdgcn_mfma_f32_16x16x16bf16_1k(v1, pf[1][1], od[1][df], 0, 0, 0);
        od[0][df] = __builtin_amdgcn_mfma_f32_16x16x16bf16_1k(v2, pf[0][2], od[0][df], 0, 0, 0);
        od[1][df] = __builtin_amdgcn_mfma_f32_16x16x16bf16_1k(v2, pf[1][2], od[1][df], 0, 0, 0);
        od[0][df] = __builtin_amdgcn_mfma_f32_16x16x16bf16_1k(v3, pf[0][3], od[0][df], 0, 0, 0);
        od[1][df] = __builtin_amdgcn_mfma_f32_16x16x16bf16_1k(v3, pf[1][3], od[1][df], 0, 0, 0);
      }
      __builtin_amdgcn_s_setprio(0);
    } // t

    // ---- cross-group merge: w+4 partials -> w (same q rows, complementary tiles) ----
    __syncthreads();                       // all tile reads done; Ks free as scratch
    if (w >= 4) {
      float* p = scr + (size_t)(tid - 256) * 36;    // 144B/thread, 16B-aligned
      #pragma unroll
      for (int qgi = 0; qgi < 2; qgi++)
        #pragma unroll
        for (int df = 0; df < 4; df++)
          *(f32x4*)(p + qgi*16 + df*4) = od[qgi][df];
      p[32] = ls[0]; p[33] = ls[1];
    }
    __syncthreads();
    if (w < 4) {
      const float* p = scr + (size_t)tid * 36;
      #pragma unroll
      for (int qgi = 0; qgi < 2; qgi++)
        #pragma unroll
        for (int df = 0; df < 4; df++)
          od[qgi][df] += *(const f32x4*)(p + qgi*16 + df*4);
      ls[0] += p[32]; ls[1] += p[33];
      // reduce l across quads (q id depends only on lane&15)
      #pragma unroll
      for (int qgi = 0; qgi < 2; qgi++) {
        ls[qgi] += __shfl_xor(ls[qgi], 16);
        ls[qgi] += __shfl_xor(ls[qgi], 32);
      }
      #pragma unroll
      for (int qgi = 0; qgi < 2; qgi++) {
        float f = ((rep < 2) ? SCL2F : 1.0f) / ls[qgi];
        #pragma unroll
        for (int df = 0; df < 4; df++) {
          Pack4 pk;
          #pragma unroll
          for (int r = 0; r < 4; r++)
            pk.e[r] = __builtin_bit_cast(unsigned short, (__bf16)(od[qgi][df][r] * f));
          *(us4*)&QC[(wq*32 + qgi*16 + lrow)*LDQ + df*16 + quad*4] = pk.v;
        }
      }
    }
    __syncthreads();   // QC complete; scratch reads done
    if (rep < 2) {   // reload chained Q frags (all 8 waves, rows wq*32..)
      #pragma unroll
      for (int qgi = 0; qgi < 2; qgi++) {
        qb[qgi][0] = *(const bf16x8*)&QC[(wq*32 + qgi*16 + lrow)*LDQ + quad*8];
        qb[qgi][1] = *(const bf16x8*)&QC[(wq*32 + qgi*16 + lrow)*LDQ + 32 + quad*8];
      }
      __syncthreads();   // reloads done before next rep's stores to Vs/Ks
    }
  } // rep

  {   // coalesced ctx store from QC
    unsigned short* dst = cbase + (size_t)(qt*128 + qrow)*HD + qc0;
    *(uint4*)dst       = *(const uint4*)&QC[qrow*LDQ + qc0];
    *(uint4*)(dst + 8) = *(const uint4*)&QC[qrow*LDQ + qc0 + 8];
  }
}

// ---------------- out projection: 128x64x64 tiles, async staging, swizzled -------
__global__ __launch_bounds__(256) void out_gemm(
    const unsigned short* __restrict__ ctx, const unsigned short* __restrict__ owb,
    const float* __restrict__ bias, float* __restrict__ out)
{
  __shared__ __align__(16) unsigned short As[128*64];
  __shared__ __align__(16) unsigned short Bs[64*64];
  const int tid = threadIdx.x;
  const int m0 = blockIdx.y * 128, n0 = blockIdx.x * 64;
  const int wave = tid >> 6, lane = tid & 63;
  const int wm = (wave >> 1) * 64, wn = (wave & 1) * 32;
  const int lrow = lane & 15, quad = lane >> 4;

  const int dr = lane >> 3, pg = lane & 7;
  const int sg = (pg ^ dr) * 8;
  size_t aoff[4]; unsigned short* lA[4];
  #pragma unroll
  for (int i = 0; i < 4; i++) {
    int c = wave*4 + i;
    int row = m0 + c*8 + dr;
    aoff[i] = ((size_t)((row >> 11)*NHEADS)*SEQ + (row & 2047))*HD + sg;
    lA[i] = &As[c*512];
  }
  const unsigned short* gB[2]; unsigned short* lB[2];
  #pragma unroll
  for (int j = 0; j < 2; j++) {
    int c = wave*2 + j;
    gB[j] = owb + (size_t)(n0 + c*8 + dr) * D_MODEL + sg;
    lB[j] = &Bs[c*512];
  }
  const int px0 = (quad ^ (lrow & 7)) * 8;
  const int px1 = ((quad + 4) ^ (lrow & 7)) * 8;

  f32x4 acc[4][2];
  #pragma unroll
  for (int i = 0; i < 4; i++)
    #pragma unroll
    for (int j = 0; j < 2; j++) acc[i][j] = (f32x4){0.f,0.f,0.f,0.f};

  for (int k0 = 0; k0 < D_MODEL; k0 += 64) {
    size_t hoff = (size_t)(k0 >> 6) * SEQ * HD;
    __syncthreads();
    #pragma unroll
    for (int i = 0; i < 4; i++) gl_lds16(ctx + aoff[i] + hoff, lA[i]);
    #pragma unroll
    for (int j = 0; j < 2; j++) gl_lds16(gB[j] + k0, lB[j]);
    __syncthreads();
    bf16x8 af[4][2], bfr[2][2];
    #pragma unroll
    for (int mf = 0; mf < 4; mf++) {
      int row = wm + mf*16 + lrow;
      af[mf][0] = *(const bf16x8*)&As[row*64 + px0];
      af[mf][1] = *(const bf16x8*)&As[row*64 + px1];
    }
    #pragma unroll
    for (int nb = 0; nb < 2; nb++) {
      int row = wn + nb*16 + lrow;
      bfr[nb][0] = *(const bf16x8*)&Bs[row*64 + px0];
      bfr[nb][1] = *(const bf16x8*)&Bs[row*64 + px1];
    }
    #pragma unroll
    for (int h = 0; h < 2; h++)
      #pragma unroll
      for (int mf = 0; mf < 4; mf++)
        #pragma unroll
        for (int nb = 0; nb < 2; nb++)
          acc[mf][nb] = __builtin_amdgcn_mfma_f32_16x16x32_bf16(af[mf][h], bfr[nb][h], acc[mf][nb], 0, 0, 0);
  }

  #pragma unroll
  for (int mf = 0; mf < 4; mf++) {
    #pragma unroll
    for (int nb = 0; nb < 2; nb++) {
      #pragma unroll
      for (int r = 0; r < 4; r++) {
        int mm = m0 + wm + mf*16 + quad*4 + r;
        int n  = n0 + wn + nb*16 + lrow;
        out[(size_t)mm * D_MODEL + n] = acc[mf][nb][r] + bias[n];
      }
    }
  }
}

extern "C" void kernel_launch(void* const* d_in, const int* in_sizes, int n_in,
                              void* d_out, int out_size, void* d_ws, size_t ws_size,
                              hipStream_t stream) {
  (void)in_sizes; (void)n_in; (void)out_size; (void)ws_size;
  const float* x      = (const float*)d_in[0];
  const float* Wqkv_w = (const float*)d_in[1];
  const float* Wqkv_b = (const float*)d_in[2];
  const float* out_w  = (const float*)d_in[3];
  const float* out_b  = (const float*)d_in[4];
  float* out = (float*)d_out;

  unsigned short* ws = (unsigned short*)d_ws;
  unsigned short* xb  = ws;                              // 4.19M elems; reused as ctx
  unsigned short* wqb = ws + CVT_N1;                     // 3.15M
  unsigned short* owb = ws + CVT_N1 + CVT_N2;            // 1.05M
  unsigned short* q   = ws + CVT_N1 + CVT_N2 + CVT_N3;   // 4.19M each
  unsigned short* k   = q + (size_t)NROWS*D_MODEL;
  unsigned short* vT  = k + (size_t)NROWS*D_MODEL;       // [bh][d][s] transposed
  unsigned short* ctx = xb;                              // alias: xb dead after qkv

  cvt_all<<<(CVT_N1+CVT_N2+CVT_N3)/(256*8), 256, 0, stream>>>(x, Wqkv_w, out_w, xb, wqb, owb);
  qkv_gemm<<<dim3(NQKV/128, NROWS/128), 256, 0, stream>>>(xb, wqb, Wqkv_b, q, k, vT);
  attn3<<<dim3(BATCH*NHEADS, SEQ/128), 512, 0, stream>>>(q, k, vT, ctx);
  out_gemm<<<dim3(D_MODEL/64, NROWS/128), 256, 0, stream>>>(ctx, owb, out_b, out);
}

// Round 9
// 250.900 us; speedup vs baseline: 1.0594x; 1.0594x over previous
//
#include <hip/hip_runtime.h>

// MHR_76965813945133: x->QKV proj -> 3x causal MHA (Q<-ctx, K/V fixed) -> out proj.
// B=2, S=2048, D=1024, NH=16, HD=64. bf16 MFMA compute, fp32 accum.
// R19: split-KV, spill-fixed. R18 proved the LDS win (conflicts 13.3M->6.95M) but
//      spilled ~110MB (launch_bounds(512,4) => ~64 arch VGPR cap on gfx950's unified
//      file; sc[2][4]+od+qb+prefetch exceeded it -> FETCH 63MB/WRITE 68MB, 143us).
//      Fix: (a) launch_bounds(512,2) — LDS already binds 2 blocks/CU, reg cap was
//      artificial; (b) fuse softmax per-sf (mask+exp2+pack right after each sf's
//      QK^T MFMAs) so sc[2][4] is never whole-array live: peak ~100 regs (~68 arch
//      + 32 acc) < 128 => 2 blocks/CU preserved, no spill. Rest = R18: waves 0-3/4-7
//      share 128 q rows, split even/odd KV tiles; merge via Ks scratch per rep.

#define D_MODEL 1024
#define NHEADS  16
#define HD      64
#define SEQ     2048
#define BATCH   2
#define NROWS   (BATCH*SEQ)   // 4096
#define NQKV    (3*D_MODEL)   // 3072
#define SCL2F   0.1803368801111601f      // 0.125 * log2(e)
#define MASK2   (-14426.950408889634f)   // -10000 * log2(e)

typedef __bf16 bf16x8 __attribute__((ext_vector_type(8)));
typedef float  f32x4  __attribute__((ext_vector_type(4)));
typedef unsigned short us8 __attribute__((ext_vector_type(8)));
typedef unsigned short us4 __attribute__((ext_vector_type(4)));
typedef short  s16x4  __attribute__((ext_vector_type(4)));

__device__ __forceinline__ unsigned short f2bf(float f) {
  unsigned int u = __float_as_uint(f);
  u = (u + 0x7fffu + ((u >> 16) & 1u)) >> 16;   // RNE
  return (unsigned short)u;
}

union Pack8 { us8 v; unsigned short e[8]; };
union Pack4 { us4 v; unsigned short e[4]; };

__device__ __forceinline__ us8 cvt8(const float4 &a, const float4 &b) {
  Pack8 p;
  p.e[0]=f2bf(a.x); p.e[1]=f2bf(a.y); p.e[2]=f2bf(a.z); p.e[3]=f2bf(a.w);
  p.e[4]=f2bf(b.x); p.e[5]=f2bf(b.y); p.e[6]=f2bf(b.z); p.e[7]=f2bf(b.w);
  return p.v;
}

__device__ __forceinline__ void gl_lds16(const unsigned short* g, unsigned short* l) {
  __builtin_amdgcn_global_load_lds(
      (const __attribute__((address_space(1))) unsigned int*)g,
      (__attribute__((address_space(3))) unsigned int*)l, 16, 0, 0);
}

// ---------------- fp32 -> bf16 pre-convert (x, Wqkv_w, out_w) --------------------
#define CVT_N1 (NROWS*D_MODEL)    // 4194304
#define CVT_N2 (NQKV*D_MODEL)     // 3145728
#define CVT_N3 (D_MODEL*D_MODEL)  // 1048576

__global__ __launch_bounds__(256) void cvt_all(
    const float* __restrict__ x, const float* __restrict__ wq,
    const float* __restrict__ ow,
    unsigned short* __restrict__ xb, unsigned short* __restrict__ wqb,
    unsigned short* __restrict__ owb)
{
  size_t i = ((size_t)blockIdx.x * 256 + threadIdx.x) * 8;
  const float* src; unsigned short* dst; size_t off;
  if (i < CVT_N1)                { src = x;  dst = xb;  off = i; }
  else if (i < CVT_N1 + CVT_N2)  { src = wq; dst = wqb; off = i - CVT_N1; }
  else                           { src = ow; dst = owb; off = i - CVT_N1 - CVT_N2; }
  float4 a = *(const float4*)(src + off);
  float4 b = *(const float4*)(src + off + 4);
  *(us8*)(dst + off) = cvt8(a, b);
}

// ---------------- QKV GEMM: 128x128x64 tiles, async staging, XOR swizzle ---------
__global__ __launch_bounds__(256) void qkv_gemm(
    const unsigned short* __restrict__ xb, const unsigned short* __restrict__ wqb,
    const float* __restrict__ bias,
    unsigned short* __restrict__ q, unsigned short* __restrict__ k,
    unsigned short* __restrict__ vT)
{
  __shared__ __align__(16) unsigned short As[128*64];
  __shared__ __align__(16) unsigned short Bs[128*64];
  const int tid = threadIdx.x;
  const int m0 = blockIdx.y * 128, n0 = blockIdx.x * 128;
  const int wave = tid >> 6, lane = tid & 63;
  const int wm = (wave >> 1) * 64, wn = (wave & 1) * 64;
  const int lrow = lane & 15, quad = lane >> 4;

  const int dr = lane >> 3;          // row within 8-row chunk
  const int pg = lane & 7;           // physical 16B slot within row
  const int sg = (pg ^ dr) * 8;      // swizzled source column (elems)
  const unsigned short* gA[4]; const unsigned short* gB[4];
  unsigned short *lA[4], *lB[4];
  #pragma unroll
  for (int i = 0; i < 4; i++) {
    int c = wave*4 + i;
    gA[i] = xb  + (size_t)(m0 + c*8 + dr) * D_MODEL + sg;
    gB[i] = wqb + (size_t)(n0 + c*8 + dr) * D_MODEL + sg;
    lA[i] = &As[c*512];
    lB[i] = &Bs[c*512];
  }
  const int px0 = (quad ^ (lrow & 7)) * 8;
  const int px1 = ((quad + 4) ^ (lrow & 7)) * 8;

  f32x4 acc[4][4];
  #pragma unroll
  for (int i = 0; i < 4; i++)
    #pragma unroll
    for (int j = 0; j < 4; j++) acc[i][j] = (f32x4){0.f,0.f,0.f,0.f};

  for (int k0 = 0; k0 < D_MODEL; k0 += 64) {
    __syncthreads();
    #pragma unroll
    for (int i = 0; i < 4; i++) { gl_lds16(gA[i] + k0, lA[i]); gl_lds16(gB[i] + k0, lB[i]); }
    __syncthreads();
    bf16x8 af[4][2], bfr[4][2];
    #pragma unroll
    for (int mf = 0; mf < 4; mf++) {
      int row = wm + mf*16 + lrow;
      af[mf][0] = *(const bf16x8*)&As[row*64 + px0];
      af[mf][1] = *(const bf16x8*)&As[row*64 + px1];
    }
    #pragma unroll
    for (int nb = 0; nb < 4; nb++) {
      int row = wn + nb*16 + lrow;
      bfr[nb][0] = *(const bf16x8*)&Bs[row*64 + px0];
      bfr[nb][1] = *(const bf16x8*)&Bs[row*64 + px1];
    }
    #pragma unroll
    for (int h = 0; h < 2; h++)
      #pragma unroll
      for (int mf = 0; mf < 4; mf++)
        #pragma unroll
        for (int nb = 0; nb < 4; nb++)
          acc[mf][nb] = __builtin_amdgcn_mfma_f32_16x16x32_bf16(af[mf][h], bfr[nb][h], acc[mf][nb], 0, 0, 0);
  }

  #pragma unroll
  for (int mf = 0; mf < 4; mf++) {
    #pragma unroll
    for (int nb = 0; nb < 4; nb++) {
      int n = n0 + wn + nb*16 + lrow;
      int which = n >> 10;
      int h  = (n >> 6) & 15;
      int hd = n & 63;
      int mb = m0 + wm + mf*16 + quad*4;
      int b  = mb >> 11;
      int s  = mb & 2047;
      float bi = bias[n];
      if (which == 2) {
        Pack4 p4;
        #pragma unroll
        for (int r = 0; r < 4; r++) p4.e[r] = f2bf(acc[mf][nb][r] + bi);
        *(us4*)&vT[((size_t)((b*NHEADS + h)*HD + hd))*SEQ + s] = p4.v;
      } else {
        unsigned short* dst = (which == 0) ? q : k;
        float scl = (which == 0) ? SCL2F : 1.0f;
        #pragma unroll
        for (int r = 0; r < 4; r++)
          dst[(size_t)((b*NHEADS + h)*SEQ + s + r)*HD + hd] = f2bf((acc[mf][nb][r] + bi) * scl);
      }
    }
  }
}

// ---------------- fused 3-rep causal flash attention ------------------------------
// R19: 512-thr blocks (8 waves), q-tile 128. Waves 0-3 / 4-7 own the SAME 128 q
// rows (32/wave, dual-qgi); group A (w<4) computes even tiles, group B (w>=4) odd
// tiles of each staged pair. Per-sf fused softmax (low reg liveness). Per-rep merge
// via Ks scratch. Grid (32,16) mirror, 2 blocks/CU (LDS-bound). 1 barrier/pair.
#define LDQ 72   // 144B rows: b128 groups (lrow+quad)%8 -> bank-uniform (R9 errata)

__global__ __launch_bounds__(512, 2) void attn3(
    const unsigned short* __restrict__ qg,
    const unsigned short* __restrict__ kg,
    const unsigned short* __restrict__ vTg,
    unsigned short* __restrict__ ctx)
{
  __shared__ __align__(16) unsigned short Ks[4][64*LDQ];
  __shared__ __align__(16) unsigned short Vs[4][64*LDQ];   // Vs[d][s]; [0..1] = Q-chain
  unsigned short* QC = &Vs[0][0];                          // 128 rows x LDQ
  float* scr = (float*)&Ks[0][0];                          // merge scratch (36,864B)

  const int tid  = threadIdx.x;
  const int w    = tid >> 6, lane = tid & 63;              // w = 0..7
  const int lrow = lane & 15, quad = lane >> 4;
  const int wq = w & 3;                            // q-row group (shared by w, w+4)
  const int hf = w >> 2;                           // tile-half: 0=even, 1=odd
  const int bh = blockIdx.x;
  const int yy = blockIdx.y;
  const int base = (blockIdx.x + yy) & 7;          // 0..7 (mirror permutation)
  const int qt = (yy < 8) ? base : (15 - base);
  const unsigned short* qbase = qg  + (size_t)bh * SEQ * HD;
  const unsigned short* kbase = kg  + (size_t)bh * SEQ * HD;
  const unsigned short* vbase = vTg + (size_t)bh * HD * SEQ;
  unsigned short* cbase = ctx + (size_t)bh * SEQ * HD;

  const int srow = tid >> 3;                       // 64x64 staging: 8 thr/row
  const int sco  = (tid & 7) * 8;                  // one uint4 per thread per tile
  const int qrow = tid >> 2, qc0 = (tid & 3) * 16; // 128-row Q map (2 uint4/thr)

  // stage Q tile (rows qt*128..+127, pre-scaled) into QC
  {
    const unsigned short* src = qbase + (size_t)(qt*128 + qrow)*HD + qc0;
    *(uint4*)&QC[qrow*LDQ + qc0]     = *(const uint4*)src;
    *(uint4*)&QC[qrow*LDQ + qc0 + 8] = *(const uint4*)(src + 8);
  }
  __syncthreads();

  // Q as K=32 B-operand frags: B[k=d=quad*8+j][n=q=lane&15]; 32 q-rows per wave-pair
  bf16x8 qb[2][2];
  #pragma unroll
  for (int qgi = 0; qgi < 2; qgi++) {
    qb[qgi][0] = *(const bf16x8*)&QC[(wq*32 + qgi*16 + lrow)*LDQ + quad*8];
    qb[qgi][1] = *(const bf16x8*)&QC[(wq*32 + qgi*16 + lrow)*LDQ + 32 + quad*8];
  }
  __syncthreads();   // qb reads done before first stores overwrite Vs

  const int qwbase = qt*128 + wq*32;  // this wave's lowest q row
  const int npair = qt + 1;           // tile pairs (tiles 2t, 2t+1); last = 2qt+1

  for (int rep = 0; rep < 3; ++rep) {
    f32x4 od[2][4];
    #pragma unroll
    for (int qgi = 0; qgi < 2; qgi++)
      #pragma unroll
      for (int df = 0; df < 4; df++) od[qgi][df] = (f32x4){0.f,0.f,0.f,0.f};
    float ls[2] = {0.f, 0.f};

    // prefetch pair 0 (tiles 0,1): 2 uint4 K + 2 uint4 V per thread
    uint4 ka, kb, va, vb;
    {
      const unsigned short* ks = kbase + (size_t)srow*HD + sco;
      ka = *(const uint4*)ks;  kb = *(const uint4*)(ks + 64*HD);
      const unsigned short* vs = vbase + (size_t)srow*SEQ + sco;
      va = *(const uint4*)vs;  vb = *(const uint4*)(vs + 64);
    }

    for (int t = 0; t < npair; ++t) {
      const int pb = (t & 1) * 2;    // buffer pair base {pb, pb+1}
      *(uint4*)&Ks[pb][srow*LDQ + sco]   = ka;
      *(uint4*)&Ks[pb+1][srow*LDQ + sco] = kb;
      *(uint4*)&Vs[pb][srow*LDQ + sco]   = va;
      *(uint4*)&Vs[pb+1][srow*LDQ + sco] = vb;
      if (t + 1 < npair) {   // prefetch next pair (tiles 2t+2, 2t+3)
        const unsigned short* ks = kbase + (size_t)((2*t+2)*64 + srow)*HD + sco;
        ka = *(const uint4*)ks;  kb = *(const uint4*)(ks + 64*HD);
        const unsigned short* vs = vbase + (size_t)srow*SEQ + (2*t+2)*64 + sco;
        va = *(const uint4*)vs;  vb = *(const uint4*)(vs + 64);
      }
      __syncthreads();   // ONE barrier per pair (2 tiles)

      // this wave's single tile of the pair
      const int bb = pb + hf;
      const int sbase = (2*t + hf) * 64;
      if (sbase > qwbase + 31) continue;   // wave fully masked for this tile
      const bool needmask = (sbase + 63 > qwbase);
      // scores + softmax fused per sf: sc[2][4] never whole-array live
      s16x4 pf[2][4];
      #pragma unroll
      for (int sf = 0; sf < 4; sf++) {
        bf16x8 a0 = *(const bf16x8*)&Ks[bb][(sf*16 + lrow)*LDQ + quad*8];
        bf16x8 a1 = *(const bf16x8*)&Ks[bb][(sf*16 + lrow)*LDQ + 32 + quad*8];
        f32x4 z0 = (f32x4){0.f,0.f,0.f,0.f}, z1 = (f32x4){0.f,0.f,0.f,0.f};
        __builtin_amdgcn_s_setprio(1);
        z0 = __builtin_amdgcn_mfma_f32_16x16x32_bf16(a0, qb[0][0], z0, 0, 0, 0);
        z1 = __builtin_amdgcn_mfma_f32_16x16x32_bf16(a0, qb[1][0], z1, 0, 0, 0);
        z0 = __builtin_amdgcn_mfma_f32_16x16x32_bf16(a1, qb[0][1], z0, 0, 0, 0);
        z1 = __builtin_amdgcn_mfma_f32_16x16x32_bf16(a1, qb[1][1], z1, 0, 0, 0);
        __builtin_amdgcn_s_setprio(0);
        if (needmask) {
          int sb = sbase + sf*16 + quad*4;
          int ql0 = qwbase + lrow, ql1 = ql0 + 16;
          #pragma unroll
          for (int r = 0; r < 4; r++) {
            if (sb + r > ql0) z0[r] += MASK2;
            if (sb + r > ql1) z1[r] += MASK2;
          }
        }
        Pack4 pk0, pk1;
        float lp0 = 0.f, lp1 = 0.f;
        #pragma unroll
        for (int r = 0; r < 4; r++) {
          float p0 = __builtin_amdgcn_exp2f(z0[r]);
          float p1 = __builtin_amdgcn_exp2f(z1[r]);
          lp0 += p0; lp1 += p1;
          pk0.e[r] = __builtin_bit_cast(unsigned short, (__bf16)p0);
          pk1.e[r] = __builtin_bit_cast(unsigned short, (__bf16)p1);
        }
        pf[0][sf] = __builtin_bit_cast(s16x4, pk0.v);
        pf[1][sf] = __builtin_bit_cast(s16x4, pk1.v);
        ls[0] += lp0; ls[1] += lp1;
      }
      // PV: O^T += V^T * P^T (K=16), both qgi share the V frags
      __builtin_amdgcn_s_setprio(1);
      #pragma unroll
      for (int df = 0; df < 4; df++) {
        s16x4 v0 = *(const s16x4*)&Vs[bb][(df*16 + lrow)*LDQ +  0 + quad*4];
        s16x4 v1 = *(const s16x4*)&Vs[bb][(df*16 + lrow)*LDQ + 16 + quad*4];
        s16x4 v2 = *(const s16x4*)&Vs[bb][(df*16 + lrow)*LDQ + 32 + quad*4];
        s16x4 v3 = *(const s16x4*)&Vs[bb][(df*16 + lrow)*LDQ + 48 + quad*4];
        od[0][df] = __builtin_amdgcn_mfma_f32_16x16x16bf16_1k(v0, pf[0][0], od[0][df], 0, 0, 0);
        od[1][df] = __builtin_amdgcn_mfma_f32_16x16x16bf16_1k(v0, pf[1][0], od[1][df], 0, 0, 0);
        od[0][df] = __builtin_amdgcn_mfma_f32_16x16x16bf16_1k(v1, pf[0][1], od[0][df], 0, 0, 0);
        od[1][df] = __builtin_amdgcn_mfma_f32_16x16x16bf16_1k(v1, pf[1][1], od[1][df], 0, 0, 0);
        od[0][df] = __builtin_amdgcn_mfma_f32_16x16x16bf16_1k(v2, pf[0][2], od[0][df], 0, 0, 0);
        od[1][df] = __builtin_amdgcn_mfma_f32_16x16x16bf16_1k(v2, pf[1][2], od[1][df], 0, 0, 0);
        od[0][df] = __builtin_amdgcn_mfma_f32_16x16x16bf16_1k(v3, pf[0][3], od[0][df], 0, 0, 0);
        od[1][df] = __builtin_amdgcn_mfma_f32_16x16x16bf16_1k(v3, pf[1][3], od[1][df], 0, 0, 0);
      }
      __builtin_amdgcn_s_setprio(0);
    } // t

    // ---- cross-group merge: w+4 partials -> w (same q rows, complementary tiles) ----
    __syncthreads();                       // all tile reads done; Ks free as scratch
    if (w >= 4) {
      float* p = scr + (size_t)(tid - 256) * 36;    // 144B/thread, 16B-aligned
      #pragma unroll
      for (int qgi = 0; qgi < 2; qgi++)
        #pragma unroll
        for (int df = 0; df < 4; df++)
          *(f32x4*)(p + qgi*16 + df*4) = od[qgi][df];
      p[32] = ls[0]; p[33] = ls[1];
    }
    __syncthreads();
    if (w < 4) {
      const float* p = scr + (size_t)tid * 36;
      #pragma unroll
      for (int qgi = 0; qgi < 2; qgi++)
        #pragma unroll
        for (int df = 0; df < 4; df++)
          od[qgi][df] += *(const f32x4*)(p + qgi*16 + df*4);
      ls[0] += p[32]; ls[1] += p[33];
      // reduce l across quads (q id depends only on lane&15)
      #pragma unroll
      for (int qgi = 0; qgi < 2; qgi++) {
        ls[qgi] += __shfl_xor(ls[qgi], 16);
        ls[qgi] += __shfl_xor(ls[qgi], 32);
      }
      #pragma unroll
      for (int qgi = 0; qgi < 2; qgi++) {
        float f = ((rep < 2) ? SCL2F : 1.0f) / ls[qgi];
        #pragma unroll
        for (int df = 0; df < 4; df++) {
          Pack4 pk;
          #pragma unroll
          for (int r = 0; r < 4; r++)
            pk.e[r] = __builtin_bit_cast(unsigned short, (__bf16)(od[qgi][df][r] * f));
          *(us4*)&QC[(wq*32 + qgi*16 + lrow)*LDQ + df*16 + quad*4] = pk.v;
        }
      }
    }
    __syncthreads();   // QC complete; scratch reads done
    if (rep < 2) {   // reload chained Q frags (all 8 waves, rows wq*32..)
      #pragma unroll
      for (int qgi = 0; qgi < 2; qgi++) {
        qb[qgi][0] = *(const bf16x8*)&QC[(wq*32 + qgi*16 + lrow)*LDQ + quad*8];
        qb[qgi][1] = *(const bf16x8*)&QC[(wq*32 + qgi*16 + lrow)*LDQ + 32 + quad*8];
      }
      __syncthreads();   // reloads done before next rep's stores to Vs/Ks
    }
  } // rep

  {   // coalesced ctx store from QC
    unsigned short* dst = cbase + (size_t)(qt*128 + qrow)*HD + qc0;
    *(uint4*)dst       = *(const uint4*)&QC[qrow*LDQ + qc0];
    *(uint4*)(dst + 8) = *(const uint4*)&QC[qrow*LDQ + qc0 + 8];
  }
}

// ---------------- out projection: 128x64x64 tiles, async staging, swizzled -------
__global__ __launch_bounds__(256) void out_gemm(
    const unsigned short* __restrict__ ctx, const unsigned short* __restrict__ owb,
    const float* __restrict__ bias, float* __restrict__ out)
{
  __shared__ __align__(16) unsigned short As[128*64];
  __shared__ __align__(16) unsigned short Bs[64*64];
  const int tid = threadIdx.x;
  const int m0 = blockIdx.y * 128, n0 = blockIdx.x * 64;
  const int wave = tid >> 6, lane = tid & 63;
  const int wm = (wave >> 1) * 64, wn = (wave & 1) * 32;
  const int lrow = lane & 15, quad = lane >> 4;

  const int dr = lane >> 3, pg = lane & 7;
  const int sg = (pg ^ dr) * 8;
  size_t aoff[4]; unsigned short* lA[4];
  #pragma unroll
  for (int i = 0; i < 4; i++) {
    int c = wave*4 + i;
    int row = m0 + c*8 + dr;
    aoff[i] = ((size_t)((row >> 11)*NHEADS)*SEQ + (row & 2047))*HD + sg;
    lA[i] = &As[c*512];
  }
  const unsigned short* gB[2]; unsigned short* lB[2];
  #pragma unroll
  for (int j = 0; j < 2; j++) {
    int c = wave*2 + j;
    gB[j] = owb + (size_t)(n0 + c*8 + dr) * D_MODEL + sg;
    lB[j] = &Bs[c*512];
  }
  const int px0 = (quad ^ (lrow & 7)) * 8;
  const int px1 = ((quad + 4) ^ (lrow & 7)) * 8;

  f32x4 acc[4][2];
  #pragma unroll
  for (int i = 0; i < 4; i++)
    #pragma unroll
    for (int j = 0; j < 2; j++) acc[i][j] = (f32x4){0.f,0.f,0.f,0.f};

  for (int k0 = 0; k0 < D_MODEL; k0 += 64) {
    size_t hoff = (size_t)(k0 >> 6) * SEQ * HD;
    __syncthreads();
    #pragma unroll
    for (int i = 0; i < 4; i++) gl_lds16(ctx + aoff[i] + hoff, lA[i]);
    #pragma unroll
    for (int j = 0; j < 2; j++) gl_lds16(gB[j] + k0, lB[j]);
    __syncthreads();
    bf16x8 af[4][2], bfr[2][2];
    #pragma unroll
    for (int mf = 0; mf < 4; mf++) {
      int row = wm + mf*16 + lrow;
      af[mf][0] = *(const bf16x8*)&As[row*64 + px0];
      af[mf][1] = *(const bf16x8*)&As[row*64 + px1];
    }
    #pragma unroll
    for (int nb = 0; nb < 2; nb++) {
      int row = wn + nb*16 + lrow;
      bfr[nb][0] = *(const bf16x8*)&Bs[row*64 + px0];
      bfr[nb][1] = *(const bf16x8*)&Bs[row*64 + px1];
    }
    #pragma unroll
    for (int h = 0; h < 2; h++)
      #pragma unroll
      for (int mf = 0; mf < 4; mf++)
        #pragma unroll
        for (int nb = 0; nb < 2; nb++)
          acc[mf][nb] = __builtin_amdgcn_mfma_f32_16x16x32_bf16(af[mf][h], bfr[nb][h], acc[mf][nb], 0, 0, 0);
  }

  #pragma unroll
  for (int mf = 0; mf < 4; mf++) {
    #pragma unroll
    for (int nb = 0; nb < 2; nb++) {
      #pragma unroll
      for (int r = 0; r < 4; r++) {
        int mm = m0 + wm + mf*16 + quad*4 + r;
        int n  = n0 + wn + nb*16 + lrow;
        out[(size_t)mm * D_MODEL + n] = acc[mf][nb][r] + bias[n];
      }
    }
  }
}

extern "C" void kernel_launch(void* const* d_in, const int* in_sizes, int n_in,
                              void* d_out, int out_size, void* d_ws, size_t ws_size,
                              hipStream_t stream) {
  (void)in_sizes; (void)n_in; (void)out_size; (void)ws_size;
  const float* x      = (const float*)d_in[0];
  const float* Wqkv_w = (const float*)d_in[1];
  const float* Wqkv_b = (const float*)d_in[2];
  const float* out_w  = (const float*)d_in[3];
  const float* out_b  = (const float*)d_in[4];
  float* out = (float*)d_out;

  unsigned short* ws = (unsigned short*)d_ws;
  unsigned short* xb  = ws;                              // 4.19M elems; reused as ctx
  unsigned short* wqb = ws + CVT_N1;                     // 3.15M
  unsigned short* owb = ws + CVT_N1 + CVT_N2;            // 1.05M
  unsigned short* q   = ws + CVT_N1 + CVT_N2 + CVT_N3;   // 4.19M each
  unsigned short* k   = q + (size_t)NROWS*D_MODEL;
  unsigned short* vT  = k + (size_t)NROWS*D_MODEL;       // [bh][d][s] transposed
  unsigned short* ctx = xb;                              // alias: xb dead after qkv

  cvt_all<<<(CVT_N1+CVT_N2+CVT_N3)/(256*8), 256, 0, stream>>>(x, Wqkv_w, out_w, xb, wqb, owb);
  qkv_gemm<<<dim3(NQKV/128, NROWS/128), 256, 0, stream>>>(xb, wqb, Wqkv_b, q, k, vT);
  attn3<<<dim3(BATCH*NHEADS, SEQ/128), 512, 0, stream>>>(q, k, vT, ctx);
  out_gemm<<<dim3(D_MODEL/64, NROWS/128), 256, 0, stream>>>(ctx, owb, out_b, out);
}

// Round 10
// 219.786 us; speedup vs baseline: 1.2094x; 1.1416x over previous
//
#include <hip/hip_runtime.h>

// MHR_76965813945133: x->QKV proj -> 3x causal MHA (Q<-ctx, K/V fixed) -> out proj.
// B=2, S=2048, D=1024, NH=16, HD=64. bf16 MFMA compute, fp32 accum.
// R20: REVERT split-KV (R18/R19: conflicts halved but slower — R15 is NOT LDS-BW
//      bound; the split cost the second independent QK->exp->PV chain per pair).
//      Base = R15 exactly (94.8us: 8 waves x 16 q/wave, 4K+4V paired staging,
//      1 barrier/pair, mirror grid, setprio). ONE change: V-read bank-conflict fix.
//      V 8B reads had 16-lane groups hitting only even (or only odd) bank-pairs
//      (p = 2*lrow+4c+quad mod 16; lrow/lrow+8 alias) -> 2x on every PV V-read =
//      bulk of the 13.3M conflict cycles. Fix: swap 8B halves of each 16B V slot
//      for odd 8-row stripes. Write: flag = (srow>>3)&1 = w&1 (wave-uniform reg
//      swap). Read: elem offset ^= 4*(lrow>>3). QC (=Vs[0..1]) self-consistent.

#define D_MODEL 1024
#define NHEADS  16
#define HD      64
#define SEQ     2048
#define BATCH   2
#define NROWS   (BATCH*SEQ)   // 4096
#define NQKV    (3*D_MODEL)   // 3072
#define SCL2F   0.1803368801111601f      // 0.125 * log2(e)
#define MASK2   (-14426.950408889634f)   // -10000 * log2(e)

typedef __bf16 bf16x8 __attribute__((ext_vector_type(8)));
typedef float  f32x4  __attribute__((ext_vector_type(4)));
typedef unsigned short us8 __attribute__((ext_vector_type(8)));
typedef unsigned short us4 __attribute__((ext_vector_type(4)));
typedef short  s16x4  __attribute__((ext_vector_type(4)));

__device__ __forceinline__ unsigned short f2bf(float f) {
  unsigned int u = __float_as_uint(f);
  u = (u + 0x7fffu + ((u >> 16) & 1u)) >> 16;   // RNE
  return (unsigned short)u;
}

union Pack8 { us8 v; unsigned short e[8]; };
union Pack4 { us4 v; unsigned short e[4]; };

__device__ __forceinline__ us8 cvt8(const float4 &a, const float4 &b) {
  Pack8 p;
  p.e[0]=f2bf(a.x); p.e[1]=f2bf(a.y); p.e[2]=f2bf(a.z); p.e[3]=f2bf(a.w);
  p.e[4]=f2bf(b.x); p.e[5]=f2bf(b.y); p.e[6]=f2bf(b.z); p.e[7]=f2bf(b.w);
  return p.v;
}

__device__ __forceinline__ void gl_lds16(const unsigned short* g, unsigned short* l) {
  __builtin_amdgcn_global_load_lds(
      (const __attribute__((address_space(1))) unsigned int*)g,
      (__attribute__((address_space(3))) unsigned int*)l, 16, 0, 0);
}

// ---------------- fp32 -> bf16 pre-convert (x, Wqkv_w, out_w) --------------------
#define CVT_N1 (NROWS*D_MODEL)    // 4194304
#define CVT_N2 (NQKV*D_MODEL)     // 3145728
#define CVT_N3 (D_MODEL*D_MODEL)  // 1048576

__global__ __launch_bounds__(256) void cvt_all(
    const float* __restrict__ x, const float* __restrict__ wq,
    const float* __restrict__ ow,
    unsigned short* __restrict__ xb, unsigned short* __restrict__ wqb,
    unsigned short* __restrict__ owb)
{
  size_t i = ((size_t)blockIdx.x * 256 + threadIdx.x) * 8;
  const float* src; unsigned short* dst; size_t off;
  if (i < CVT_N1)                { src = x;  dst = xb;  off = i; }
  else if (i < CVT_N1 + CVT_N2)  { src = wq; dst = wqb; off = i - CVT_N1; }
  else                           { src = ow; dst = owb; off = i - CVT_N1 - CVT_N2; }
  float4 a = *(const float4*)(src + off);
  float4 b = *(const float4*)(src + off + 4);
  *(us8*)(dst + off) = cvt8(a, b);
}

// ---------------- QKV GEMM: 128x128x64 tiles, async staging, XOR swizzle ---------
__global__ __launch_bounds__(256) void qkv_gemm(
    const unsigned short* __restrict__ xb, const unsigned short* __restrict__ wqb,
    const float* __restrict__ bias,
    unsigned short* __restrict__ q, unsigned short* __restrict__ k,
    unsigned short* __restrict__ vT)
{
  __shared__ __align__(16) unsigned short As[128*64];
  __shared__ __align__(16) unsigned short Bs[128*64];
  const int tid = threadIdx.x;
  const int m0 = blockIdx.y * 128, n0 = blockIdx.x * 128;
  const int wave = tid >> 6, lane = tid & 63;
  const int wm = (wave >> 1) * 64, wn = (wave & 1) * 64;
  const int lrow = lane & 15, quad = lane >> 4;

  const int dr = lane >> 3;          // row within 8-row chunk
  const int pg = lane & 7;           // physical 16B slot within row
  const int sg = (pg ^ dr) * 8;      // swizzled source column (elems)
  const unsigned short* gA[4]; const unsigned short* gB[4];
  unsigned short *lA[4], *lB[4];
  #pragma unroll
  for (int i = 0; i < 4; i++) {
    int c = wave*4 + i;
    gA[i] = xb  + (size_t)(m0 + c*8 + dr) * D_MODEL + sg;
    gB[i] = wqb + (size_t)(n0 + c*8 + dr) * D_MODEL + sg;
    lA[i] = &As[c*512];
    lB[i] = &Bs[c*512];
  }
  const int px0 = (quad ^ (lrow & 7)) * 8;
  const int px1 = ((quad + 4) ^ (lrow & 7)) * 8;

  f32x4 acc[4][4];
  #pragma unroll
  for (int i = 0; i < 4; i++)
    #pragma unroll
    for (int j = 0; j < 4; j++) acc[i][j] = (f32x4){0.f,0.f,0.f,0.f};

  for (int k0 = 0; k0 < D_MODEL; k0 += 64) {
    __syncthreads();
    #pragma unroll
    for (int i = 0; i < 4; i++) { gl_lds16(gA[i] + k0, lA[i]); gl_lds16(gB[i] + k0, lB[i]); }
    __syncthreads();
    bf16x8 af[4][2], bfr[4][2];
    #pragma unroll
    for (int mf = 0; mf < 4; mf++) {
      int row = wm + mf*16 + lrow;
      af[mf][0] = *(const bf16x8*)&As[row*64 + px0];
      af[mf][1] = *(const bf16x8*)&As[row*64 + px1];
    }
    #pragma unroll
    for (int nb = 0; nb < 4; nb++) {
      int row = wn + nb*16 + lrow;
      bfr[nb][0] = *(const bf16x8*)&Bs[row*64 + px0];
      bfr[nb][1] = *(const bf16x8*)&Bs[row*64 + px1];
    }
    #pragma unroll
    for (int h = 0; h < 2; h++)
      #pragma unroll
      for (int mf = 0; mf < 4; mf++)
        #pragma unroll
        for (int nb = 0; nb < 4; nb++)
          acc[mf][nb] = __builtin_amdgcn_mfma_f32_16x16x32_bf16(af[mf][h], bfr[nb][h], acc[mf][nb], 0, 0, 0);
  }

  #pragma unroll
  for (int mf = 0; mf < 4; mf++) {
    #pragma unroll
    for (int nb = 0; nb < 4; nb++) {
      int n = n0 + wn + nb*16 + lrow;
      int which = n >> 10;
      int h  = (n >> 6) & 15;
      int hd = n & 63;
      int mb = m0 + wm + mf*16 + quad*4;
      int b  = mb >> 11;
      int s  = mb & 2047;
      float bi = bias[n];
      if (which == 2) {
        Pack4 p4;
        #pragma unroll
        for (int r = 0; r < 4; r++) p4.e[r] = f2bf(acc[mf][nb][r] + bi);
        *(us4*)&vT[((size_t)((b*NHEADS + h)*HD + hd))*SEQ + s] = p4.v;
      } else {
        unsigned short* dst = (which == 0) ? q : k;
        float scl = (which == 0) ? SCL2F : 1.0f;
        #pragma unroll
        for (int r = 0; r < 4; r++)
          dst[(size_t)((b*NHEADS + h)*SEQ + s + r)*HD + hd] = f2bf((acc[mf][nb][r] + bi) * scl);
      }
    }
  }
}

// ---------------- fused 3-rep causal flash attention ------------------------------
// R20 = R15 + V half-swap swizzle: 512-thr blocks (8 waves), 128-q tiles (16
// q/wave), grid (bh=32, y=16) mirror. 4 K + 4 V buffers: TWO tiles staged per
// barrier, 2-tile register prefetch, ONE barrier per pair. Q chained via dead Vs.
#define LDQ 72   // 144B rows: b128 groups (lrow+quad)%8 -> bank-uniform (R9 errata)

__global__ __launch_bounds__(512, 4) void attn3(
    const unsigned short* __restrict__ qg,
    const unsigned short* __restrict__ kg,
    const unsigned short* __restrict__ vTg,
    unsigned short* __restrict__ ctx)
{
  __shared__ __align__(16) unsigned short Ks[4][64*LDQ];
  __shared__ __align__(16) unsigned short Vs[4][64*LDQ];   // Vs[d][s]; [0..1] = Q-chain
  unsigned short* QC = &Vs[0][0];                          // 128 rows x LDQ

  const int tid  = threadIdx.x;
  const int w    = tid >> 6, lane = tid & 63;              // w = 0..7
  const int lrow = lane & 15, quad = lane >> 4;
  const int bh = blockIdx.x;
  const int yy = blockIdx.y;
  const int base = (blockIdx.x + yy) & 7;          // 0..7 (mirror permutation)
  const int qt = (yy < 8) ? base : (15 - base);
  const unsigned short* qbase = qg  + (size_t)bh * SEQ * HD;
  const unsigned short* kbase = kg  + (size_t)bh * SEQ * HD;
  const unsigned short* vbase = vTg + (size_t)bh * HD * SEQ;
  unsigned short* cbase = ctx + (size_t)bh * SEQ * HD;

  const int srow = tid >> 3;                       // 64x64 staging: 8 thr/row
  const int sco  = (tid & 7) * 8;                  // one uint4 per thread per tile
  const int qrow = tid >> 2, qc0 = (tid & 3) * 16; // 128-row Q map (2 uint4/thr)
  const bool vsw = (w & 1);                        // V half-swap flag (= (srow>>3)&1)
  const int vq = (quad*4) ^ ((lrow >> 3) << 2);    // swizzled V-read sub-offset

  // stage Q tile (rows qt*128..+127, pre-scaled) into QC
  {
    const unsigned short* src = qbase + (size_t)(qt*128 + qrow)*HD + qc0;
    *(uint4*)&QC[qrow*LDQ + qc0]     = *(const uint4*)src;
    *(uint4*)&QC[qrow*LDQ + qc0 + 8] = *(const uint4*)(src + 8);
  }
  __syncthreads();

  // Q as K=32 B-operand frags: B[k=d=quad*8+j][n=q=lane&15]; 16 q-rows per wave
  bf16x8 qb0 = *(const bf16x8*)&QC[(w*16 + lrow)*LDQ + quad*8];
  bf16x8 qb1 = *(const bf16x8*)&QC[(w*16 + lrow)*LDQ + 32 + quad*8];
  __syncthreads();   // qb reads done before first stores overwrite Vs

  const int qwbase = qt*128 + w*16;   // this wave's lowest q row
  const int npair = qt + 1;           // tile pairs (tiles 2t, 2t+1); last = 2qt+1

  for (int rep = 0; rep < 3; ++rep) {
    f32x4 od[4];
    #pragma unroll
    for (int df = 0; df < 4; df++) od[df] = (f32x4){0.f,0.f,0.f,0.f};
    float ls = 0.f;

    // prefetch pair 0 (tiles 0,1): 2 uint4 K + 2 uint4 V per thread
    uint4 ka, kb, va, vb;
    {
      const unsigned short* ks = kbase + (size_t)srow*HD + sco;
      ka = *(const uint4*)ks;  kb = *(const uint4*)(ks + 64*HD);
      const unsigned short* vs = vbase + (size_t)srow*SEQ + sco;
      va = *(const uint4*)vs;  vb = *(const uint4*)(vs + 64);
    }

    for (int t = 0; t < npair; ++t) {
      const int pb = (t & 1) * 2;    // buffer pair base {pb, pb+1}
      *(uint4*)&Ks[pb][srow*LDQ + sco]   = ka;
      *(uint4*)&Ks[pb+1][srow*LDQ + sco] = kb;
      {   // V stores: swap 8B halves on odd 8-row stripes (bank-conflict fix)
        uint4 vaS = vsw ? make_uint4(va.z, va.w, va.x, va.y) : va;
        uint4 vbS = vsw ? make_uint4(vb.z, vb.w, vb.x, vb.y) : vb;
        *(uint4*)&Vs[pb][srow*LDQ + sco]   = vaS;
        *(uint4*)&Vs[pb+1][srow*LDQ + sco] = vbS;
      }
      if (t + 1 < npair) {   // prefetch next pair (tiles 2t+2, 2t+3)
        const unsigned short* ks = kbase + (size_t)((2*t+2)*64 + srow)*HD + sco;
        ka = *(const uint4*)ks;  kb = *(const uint4*)(ks + 64*HD);
        const unsigned short* vs = vbase + (size_t)srow*SEQ + (2*t+2)*64 + sco;
        va = *(const uint4*)vs;  vb = *(const uint4*)(vs + 64);
      }
      __syncthreads();   // ONE barrier per pair (2 tiles)

      #pragma unroll
      for (int half = 0; half < 2; ++half) {
        const int bb = pb + half;
        const int sbase = (2*t + half) * 64;
        if (sbase > qwbase + 15) continue;   // wave fully masked for this tile
        // scores: S^T = K * Q^T (K=32)
        f32x4 sc[4];
        __builtin_amdgcn_s_setprio(1);
        #pragma unroll
        for (int sf = 0; sf < 4; sf++) {
          bf16x8 a0 = *(const bf16x8*)&Ks[bb][(sf*16 + lrow)*LDQ + quad*8];
          bf16x8 a1 = *(const bf16x8*)&Ks[bb][(sf*16 + lrow)*LDQ + 32 + quad*8];
          f32x4 z = (f32x4){0.f,0.f,0.f,0.f};
          z = __builtin_amdgcn_mfma_f32_16x16x32_bf16(a0, qb0, z, 0, 0, 0);
          z = __builtin_amdgcn_mfma_f32_16x16x32_bf16(a1, qb1, z, 0, 0, 0);
          sc[sf] = z;
        }
        __builtin_amdgcn_s_setprio(0);
        if (sbase + 63 > qwbase) {   // element mask (diag-adjacent tiles only)
          int ql = qwbase + lrow;
          #pragma unroll
          for (int sf = 0; sf < 4; sf++)
            #pragma unroll
            for (int r = 0; r < 4; r++)
              if (sbase + sf*16 + quad*4 + r > ql) sc[sf][r] += MASK2;
        }
        // p = exp2(s); P lands directly in K=16 B-layout
        s16x4 pf[4];
        float lp = 0.f;
        #pragma unroll
        for (int sf = 0; sf < 4; sf++) {
          Pack4 pk;
          #pragma unroll
          for (int r = 0; r < 4; r++) {
            float pe = __builtin_amdgcn_exp2f(sc[sf][r]);
            lp += pe;
            pk.e[r] = __builtin_bit_cast(unsigned short, (__bf16)pe);
          }
          pf[sf] = __builtin_bit_cast(s16x4, pk.v);
        }
        ls += lp;
        // PV: O^T += V^T * P^T (K=16); reads use swizzled sub-offset vq
        __builtin_amdgcn_s_setprio(1);
        #pragma unroll
        for (int df = 0; df < 4; df++) {
          s16x4 v0 = *(const s16x4*)&Vs[bb][(df*16 + lrow)*LDQ +  0 + vq];
          s16x4 v1 = *(const s16x4*)&Vs[bb][(df*16 + lrow)*LDQ + 16 + vq];
          s16x4 v2 = *(const s16x4*)&Vs[bb][(df*16 + lrow)*LDQ + 32 + vq];
          s16x4 v3 = *(const s16x4*)&Vs[bb][(df*16 + lrow)*LDQ + 48 + vq];
          od[df] = __builtin_amdgcn_mfma_f32_16x16x16bf16_1k(v0, pf[0], od[df], 0, 0, 0);
          od[df] = __builtin_amdgcn_mfma_f32_16x16x16bf16_1k(v1, pf[1], od[df], 0, 0, 0);
          od[df] = __builtin_amdgcn_mfma_f32_16x16x16bf16_1k(v2, pf[2], od[df], 0, 0, 0);
          od[df] = __builtin_amdgcn_mfma_f32_16x16x16bf16_1k(v3, pf[3], od[df], 0, 0, 0);
        }
        __builtin_amdgcn_s_setprio(0);
      } // half
    } // t

    // reduce l across quads (q id depends only on lane&15)
    ls += __shfl_xor(ls, 16);
    ls += __shfl_xor(ls, 32);

    __syncthreads();   // all Ks/Vs readers done; QC (=Vs[0..1]) is free
    {
      float f = ((rep < 2) ? SCL2F : 1.0f) / ls;
      #pragma unroll
      for (int df = 0; df < 4; df++) {
        Pack4 pk;
        #pragma unroll
        for (int r = 0; r < 4; r++)
          pk.e[r] = __builtin_bit_cast(unsigned short, (__bf16)(od[df][r] * f));
        *(us4*)&QC[(w*16 + lrow)*LDQ + df*16 + quad*4] = pk.v;
      }
    }
    __syncthreads();
    if (rep < 2) {   // reload chained Q frags
      qb0 = *(const bf16x8*)&QC[(w*16 + lrow)*LDQ + quad*8];
      qb1 = *(const bf16x8*)&QC[(w*16 + lrow)*LDQ + 32 + quad*8];
      __syncthreads();   // reloads done before next rep's stores to Vs
    }
  } // rep

  {   // coalesced ctx store from QC
    unsigned short* dst = cbase + (size_t)(qt*128 + qrow)*HD + qc0;
    *(uint4*)dst       = *(const uint4*)&QC[qrow*LDQ + qc0];
    *(uint4*)(dst + 8) = *(const uint4*)&QC[qrow*LDQ + qc0 + 8];
  }
}

// ---------------- out projection: 128x64x64 tiles, async staging, swizzled -------
__global__ __launch_bounds__(256) void out_gemm(
    const unsigned short* __restrict__ ctx, const unsigned short* __restrict__ owb,
    const float* __restrict__ bias, float* __restrict__ out)
{
  __shared__ __align__(16) unsigned short As[128*64];
  __shared__ __align__(16) unsigned short Bs[64*64];
  const int tid = threadIdx.x;
  const int m0 = blockIdx.y * 128, n0 = blockIdx.x * 64;
  const int wave = tid >> 6, lane = tid & 63;
  const int wm = (wave >> 1) * 64, wn = (wave & 1) * 32;
  const int lrow = lane & 15, quad = lane >> 4;

  const int dr = lane >> 3, pg = lane & 7;
  const int sg = (pg ^ dr) * 8;
  size_t aoff[4]; unsigned short* lA[4];
  #pragma unroll
  for (int i = 0; i < 4; i++) {
    int c = wave*4 + i;
    int row = m0 + c*8 + dr;
    aoff[i] = ((size_t)((row >> 11)*NHEADS)*SEQ + (row & 2047))*HD + sg;
    lA[i] = &As[c*512];
  }
  const unsigned short* gB[2]; unsigned short* lB[2];
  #pragma unroll
  for (int j = 0; j < 2; j++) {
    int c = wave*2 + j;
    gB[j] = owb + (size_t)(n0 + c*8 + dr) * D_MODEL + sg;
    lB[j] = &Bs[c*512];
  }
  const int px0 = (quad ^ (lrow & 7)) * 8;
  const int px1 = ((quad + 4) ^ (lrow & 7)) * 8;

  f32x4 acc[4][2];
  #pragma unroll
  for (int i = 0; i < 4; i++)
    #pragma unroll
    for (int j = 0; j < 2; j++) acc[i][j] = (f32x4){0.f,0.f,0.f,0.f};

  for (int k0 = 0; k0 < D_MODEL; k0 += 64) {
    size_t hoff = (size_t)(k0 >> 6) * SEQ * HD;
    __syncthreads();
    #pragma unroll
    for (int i = 0; i < 4; i++) gl_lds16(ctx + aoff[i] + hoff, lA[i]);
    #pragma unroll
    for (int j = 0; j < 2; j++) gl_lds16(gB[j] + k0, lB[j]);
    __syncthreads();
    bf16x8 af[4][2], bfr[2][2];
    #pragma unroll
    for (int mf = 0; mf < 4; mf++) {
      int row = wm + mf*16 + lrow;
      af[mf][0] = *(const bf16x8*)&As[row*64 + px0];
      af[mf][1] = *(const bf16x8*)&As[row*64 + px1];
    }
    #pragma unroll
    for (int nb = 0; nb < 2; nb++) {
      int row = wn + nb*16 + lrow;
      bfr[nb][0] = *(const bf16x8*)&Bs[row*64 + px0];
      bfr[nb][1] = *(const bf16x8*)&Bs[row*64 + px1];
    }
    #pragma unroll
    for (int h = 0; h < 2; h++)
      #pragma unroll
      for (int mf = 0; mf < 4; mf++)
        #pragma unroll
        for (int nb = 0; nb < 2; nb++)
          acc[mf][nb] = __builtin_amdgcn_mfma_f32_16x16x32_bf16(af[mf][h], bfr[nb][h], acc[mf][nb], 0, 0, 0);
  }

  #pragma unroll
  for (int mf = 0; mf < 4; mf++) {
    #pragma unroll
    for (int nb = 0; nb < 2; nb++) {
      #pragma unroll
      for (int r = 0; r < 4; r++) {
        int mm = m0 + wm + mf*16 + quad*4 + r;
        int n  = n0 + wn + nb*16 + lrow;
        out[(size_t)mm * D_MODEL + n] = acc[mf][nb][r] + bias[n];
      }
    }
  }
}

extern "C" void kernel_launch(void* const* d_in, const int* in_sizes, int n_in,
                              void* d_out, int out_size, void* d_ws, size_t ws_size,
                              hipStream_t stream) {
  (void)in_sizes; (void)n_in; (void)out_size; (void)ws_size;
  const float* x      = (const float*)d_in[0];
  const float* Wqkv_w = (const float*)d_in[1];
  const float* Wqkv_b = (const float*)d_in[2];
  const float* out_w  = (const float*)d_in[3];
  const float* out_b  = (const float*)d_in[4];
  float* out = (float*)d_out;

  unsigned short* ws = (unsigned short*)d_ws;
  unsigned short* xb  = ws;                              // 4.19M elems; reused as ctx
  unsigned short* wqb = ws + CVT_N1;                     // 3.15M
  unsigned short* owb = ws + CVT_N1 + CVT_N2;            // 1.05M
  unsigned short* q   = ws + CVT_N1 + CVT_N2 + CVT_N3;   // 4.19M each
  unsigned short* k   = q + (size_t)NROWS*D_MODEL;
  unsigned short* vT  = k + (size_t)NROWS*D_MODEL;       // [bh][d][s] transposed
  unsigned short* ctx = xb;                              // alias: xb dead after qkv

  cvt_all<<<(CVT_N1+CVT_N2+CVT_N3)/(256*8), 256, 0, stream>>>(x, Wqkv_w, out_w, xb, wqb, owb);
  qkv_gemm<<<dim3(NQKV/128, NROWS/128), 256, 0, stream>>>(xb, wqb, Wqkv_b, q, k, vT);
  attn3<<<dim3(BATCH*NHEADS, SEQ/128), 512, 0, stream>>>(q, k, vT, ctx);
  out_gemm<<<dim3(D_MODEL/64, NROWS/128), 256, 0, stream>>>(ctx, owb, out_b, out);
}

// Round 11
// 217.465 us; speedup vs baseline: 1.2223x; 1.0107x over previous
//
#include <hip/hip_runtime.h>

// MHR_76965813945133: x->QKV proj -> 3x causal MHA (Q<-ctx, K/V fixed) -> out proj.
// B=2, S=2048, D=1024, NH=16, HD=64. bf16 MFMA compute, fp32 accum.
// R21: attn3 = R20 (94.5us; V-swizzle kept: conflicts 13.3M->6.8M, free). New focus:
//      non-attn kernels = 125us vs ~55 ideal. qkv_gemm epilogue was store-bound:
//      vT = 8B stores at 4KB stride (~8B/64B line useful), q/k = scalar stores at
//      128B stride. Fix: stage the 128x128 output tile in LDS (As|Bs merged 32KB,
//      dead after main loop), then coalesced stores: q/k 1KB-contiguous runs/instr
//      ([s][hd] per head is 16KB linear); vT transposed [n][m] in LDS (XOR-swizzled
//      staging writes vs 16-way bank conflict) -> 256B full-line chunks. which=n0>>10
//      is block-uniform. Same arithmetic/rounding -> absmax unchanged.

#define D_MODEL 1024
#define NHEADS  16
#define HD      64
#define SEQ     2048
#define BATCH   2
#define NROWS   (BATCH*SEQ)   // 4096
#define NQKV    (3*D_MODEL)   // 3072
#define SCL2F   0.1803368801111601f      // 0.125 * log2(e)
#define MASK2   (-14426.950408889634f)   // -10000 * log2(e)

typedef __bf16 bf16x8 __attribute__((ext_vector_type(8)));
typedef float  f32x4  __attribute__((ext_vector_type(4)));
typedef unsigned short us8 __attribute__((ext_vector_type(8)));
typedef unsigned short us4 __attribute__((ext_vector_type(4)));
typedef short  s16x4  __attribute__((ext_vector_type(4)));

__device__ __forceinline__ unsigned short f2bf(float f) {
  unsigned int u = __float_as_uint(f);
  u = (u + 0x7fffu + ((u >> 16) & 1u)) >> 16;   // RNE
  return (unsigned short)u;
}

union Pack8 { us8 v; unsigned short e[8]; };
union Pack4 { us4 v; unsigned short e[4]; };

__device__ __forceinline__ us8 cvt8(const float4 &a, const float4 &b) {
  Pack8 p;
  p.e[0]=f2bf(a.x); p.e[1]=f2bf(a.y); p.e[2]=f2bf(a.z); p.e[3]=f2bf(a.w);
  p.e[4]=f2bf(b.x); p.e[5]=f2bf(b.y); p.e[6]=f2bf(b.z); p.e[7]=f2bf(b.w);
  return p.v;
}

__device__ __forceinline__ void gl_lds16(const unsigned short* g, unsigned short* l) {
  __builtin_amdgcn_global_load_lds(
      (const __attribute__((address_space(1))) unsigned int*)g,
      (__attribute__((address_space(3))) unsigned int*)l, 16, 0, 0);
}

// ---------------- fp32 -> bf16 pre-convert (x, Wqkv_w, out_w) --------------------
#define CVT_N1 (NROWS*D_MODEL)    // 4194304
#define CVT_N2 (NQKV*D_MODEL)     // 3145728
#define CVT_N3 (D_MODEL*D_MODEL)  // 1048576

__global__ __launch_bounds__(256) void cvt_all(
    const float* __restrict__ x, const float* __restrict__ wq,
    const float* __restrict__ ow,
    unsigned short* __restrict__ xb, unsigned short* __restrict__ wqb,
    unsigned short* __restrict__ owb)
{
  size_t i = ((size_t)blockIdx.x * 256 + threadIdx.x) * 8;
  const float* src; unsigned short* dst; size_t off;
  if (i < CVT_N1)                { src = x;  dst = xb;  off = i; }
  else if (i < CVT_N1 + CVT_N2)  { src = wq; dst = wqb; off = i - CVT_N1; }
  else                           { src = ow; dst = owb; off = i - CVT_N1 - CVT_N2; }
  float4 a = *(const float4*)(src + off);
  float4 b = *(const float4*)(src + off + 4);
  *(us8*)(dst + off) = cvt8(a, b);
}

// ---------------- QKV GEMM: 128x128x64 tiles, async staging, XOR swizzle ---------
// R21: LDS-staged coalesced epilogue (q/k: 1KB runs; vT: transposed 256B chunks).
__global__ __launch_bounds__(256) void qkv_gemm(
    const unsigned short* __restrict__ xb, const unsigned short* __restrict__ wqb,
    const float* __restrict__ bias,
    unsigned short* __restrict__ q, unsigned short* __restrict__ k,
    unsigned short* __restrict__ vT)
{
  __shared__ __align__(16) unsigned short smem[2*128*64];   // As | Bs; epilogue 128x128
  unsigned short* As = smem;
  unsigned short* Bs = smem + 128*64;
  const int tid = threadIdx.x;
  const int m0 = blockIdx.y * 128, n0 = blockIdx.x * 128;
  const int wave = tid >> 6, lane = tid & 63;
  const int wm = (wave >> 1) * 64, wn = (wave & 1) * 64;
  const int lrow = lane & 15, quad = lane >> 4;

  const int dr = lane >> 3;          // row within 8-row chunk
  const int pg = lane & 7;           // physical 16B slot within row
  const int sg = (pg ^ dr) * 8;      // swizzled source column (elems)
  const unsigned short* gA[4]; const unsigned short* gB[4];
  unsigned short *lA[4], *lB[4];
  #pragma unroll
  for (int i = 0; i < 4; i++) {
    int c = wave*4 + i;
    gA[i] = xb  + (size_t)(m0 + c*8 + dr) * D_MODEL + sg;
    gB[i] = wqb + (size_t)(n0 + c*8 + dr) * D_MODEL + sg;
    lA[i] = &As[c*512];
    lB[i] = &Bs[c*512];
  }
  const int px0 = (quad ^ (lrow & 7)) * 8;
  const int px1 = ((quad + 4) ^ (lrow & 7)) * 8;

  f32x4 acc[4][4];
  #pragma unroll
  for (int i = 0; i < 4; i++)
    #pragma unroll
    for (int j = 0; j < 4; j++) acc[i][j] = (f32x4){0.f,0.f,0.f,0.f};

  for (int k0 = 0; k0 < D_MODEL; k0 += 64) {
    __syncthreads();
    #pragma unroll
    for (int i = 0; i < 4; i++) { gl_lds16(gA[i] + k0, lA[i]); gl_lds16(gB[i] + k0, lB[i]); }
    __syncthreads();
    bf16x8 af[4][2], bfr[4][2];
    #pragma unroll
    for (int mf = 0; mf < 4; mf++) {
      int row = wm + mf*16 + lrow;
      af[mf][0] = *(const bf16x8*)&As[row*64 + px0];
      af[mf][1] = *(const bf16x8*)&As[row*64 + px1];
    }
    #pragma unroll
    for (int nb = 0; nb < 4; nb++) {
      int row = wn + nb*16 + lrow;
      bfr[nb][0] = *(const bf16x8*)&Bs[row*64 + px0];
      bfr[nb][1] = *(const bf16x8*)&Bs[row*64 + px1];
    }
    #pragma unroll
    for (int h = 0; h < 2; h++)
      #pragma unroll
      for (int mf = 0; mf < 4; mf++)
        #pragma unroll
        for (int nb = 0; nb < 4; nb++)
          acc[mf][nb] = __builtin_amdgcn_mfma_f32_16x16x32_bf16(af[mf][h], bfr[nb][h], acc[mf][nb], 0, 0, 0);
  }

  // -------- epilogue: LDS-staged coalesced stores (which uniform per block) ------
  const int which = n0 >> 10;        // 0=q, 1=k, 2=vT
  const int b  = m0 >> 11;           // batch (tile never straddles: 2048 % 128 == 0)
  const int s0 = m0 & 2047;
  const int h0 = (n0 & 1023) >> 6;   // first of the 2 heads in this n-tile

  __syncthreads();                   // all MFMA reads of As/Bs complete

  if (which < 2) {
    const float scl = (which == 0) ? SCL2F : 1.0f;
    #pragma unroll
    for (int nb = 0; nb < 4; nb++) {
      int n = wn + nb*16 + lrow;
      float bi = bias[n0 + n];
      #pragma unroll
      for (int mf = 0; mf < 4; mf++) {
        int m = wm + mf*16 + quad*4;
        #pragma unroll
        for (int r = 0; r < 4; r++)
          smem[(m + r)*128 + n] = f2bf((acc[mf][nb][r] + bi) * scl);
      }
    }
    __syncthreads();
    unsigned short* dstbase = (which == 0) ? q : k;
    const int hh   = wave >> 1;      // head-half of the n-range
    const int half = wave & 1;       // s-half within the head region
    unsigned short* hb = dstbase + ((size_t)((b*NHEADS + h0 + hh)*SEQ + s0))*HD;
    #pragma unroll
    for (int i = 0; i < 8; i++) {
      int off  = half*4096 + i*512 + lane*8;    // elems within 8192-elem head region
      int s    = off >> 6;
      int slot = off & 63;
      *(uint4*)(hb + off) = *(const uint4*)&smem[s*128 + hh*64 + slot];
    }
  } else {
    // vT: stage transposed [n][m] (XOR-swizzled m to spread banks), store s-major
    #pragma unroll
    for (int nb = 0; nb < 4; nb++) {
      int n = wn + nb*16 + lrow;
      float bi = bias[n0 + n];
      int sw = (n & 7) << 3;                    // bank swizzle (multiple of 8 elems)
      #pragma unroll
      for (int mf = 0; mf < 4; mf++) {
        int m = wm + mf*16 + quad*4;
        Pack4 p4;
        #pragma unroll
        for (int r = 0; r < 4; r++) p4.e[r] = f2bf(acc[mf][nb][r] + bi);
        *(us4*)&smem[n*128 + (m ^ sw)] = p4.v;
      }
    }
    __syncthreads();
    #pragma unroll
    for (int i = 0; i < 8; i++) {
      int n  = wave*32 + i*4 + (lane >> 4);     // 0..127
      int mo = (lane & 15) * 8;                 // 16B chunk within the 128-elem s-run
      int sw = (n & 7) << 3;
      unsigned short* dst = vT +
          ((size_t)((b*NHEADS + h0 + (n >> 6))*HD + (n & 63)))*SEQ + s0 + mo;
      *(uint4*)dst = *(const uint4*)&smem[n*128 + (mo ^ sw)];
    }
  }
}

// ---------------- fused 3-rep causal flash attention ------------------------------
// R21 = R20: 512-thr blocks (8 waves), 128-q tiles (16 q/wave), grid (bh=32, y=16)
// mirror. 4 K + 4 V buffers: TWO tiles staged per barrier, 2-tile register prefetch,
// ONE barrier per pair. Q chained via dead Vs. V half-swap swizzle (conflict fix).
#define LDQ 72   // 144B rows: b128 groups (lrow+quad)%8 -> bank-uniform (R9 errata)

__global__ __launch_bounds__(512, 4) void attn3(
    const unsigned short* __restrict__ qg,
    const unsigned short* __restrict__ kg,
    const unsigned short* __restrict__ vTg,
    unsigned short* __restrict__ ctx)
{
  __shared__ __align__(16) unsigned short Ks[4][64*LDQ];
  __shared__ __align__(16) unsigned short Vs[4][64*LDQ];   // Vs[d][s]; [0..1] = Q-chain
  unsigned short* QC = &Vs[0][0];                          // 128 rows x LDQ

  const int tid  = threadIdx.x;
  const int w    = tid >> 6, lane = tid & 63;              // w = 0..7
  const int lrow = lane & 15, quad = lane >> 4;
  const int bh = blockIdx.x;
  const int yy = blockIdx.y;
  const int base = (blockIdx.x + yy) & 7;          // 0..7 (mirror permutation)
  const int qt = (yy < 8) ? base : (15 - base);
  const unsigned short* qbase = qg  + (size_t)bh * SEQ * HD;
  const unsigned short* kbase = kg  + (size_t)bh * SEQ * HD;
  const unsigned short* vbase = vTg + (size_t)bh * HD * SEQ;
  unsigned short* cbase = ctx + (size_t)bh * SEQ * HD;

  const int srow = tid >> 3;                       // 64x64 staging: 8 thr/row
  const int sco  = (tid & 7) * 8;                  // one uint4 per thread per tile
  const int qrow = tid >> 2, qc0 = (tid & 3) * 16; // 128-row Q map (2 uint4/thr)
  const bool vsw = (w & 1);                        // V half-swap flag (= (srow>>3)&1)
  const int vq = (quad*4) ^ ((lrow >> 3) << 2);    // swizzled V-read sub-offset

  // stage Q tile (rows qt*128..+127, pre-scaled) into QC
  {
    const unsigned short* src = qbase + (size_t)(qt*128 + qrow)*HD + qc0;
    *(uint4*)&QC[qrow*LDQ + qc0]     = *(const uint4*)src;
    *(uint4*)&QC[qrow*LDQ + qc0 + 8] = *(const uint4*)(src + 8);
  }
  __syncthreads();

  // Q as K=32 B-operand frags: B[k=d=quad*8+j][n=q=lane&15]; 16 q-rows per wave
  bf16x8 qb0 = *(const bf16x8*)&QC[(w*16 + lrow)*LDQ + quad*8];
  bf16x8 qb1 = *(const bf16x8*)&QC[(w*16 + lrow)*LDQ + 32 + quad*8];
  __syncthreads();   // qb reads done before first stores overwrite Vs

  const int qwbase = qt*128 + w*16;   // this wave's lowest q row
  const int npair = qt + 1;           // tile pairs (tiles 2t, 2t+1); last = 2qt+1

  for (int rep = 0; rep < 3; ++rep) {
    f32x4 od[4];
    #pragma unroll
    for (int df = 0; df < 4; df++) od[df] = (f32x4){0.f,0.f,0.f,0.f};
    float ls = 0.f;

    // prefetch pair 0 (tiles 0,1): 2 uint4 K + 2 uint4 V per thread
    uint4 ka, kb, va, vb;
    {
      const unsigned short* ks = kbase + (size_t)srow*HD + sco;
      ka = *(const uint4*)ks;  kb = *(const uint4*)(ks + 64*HD);
      const unsigned short* vs = vbase + (size_t)srow*SEQ + sco;
      va = *(const uint4*)vs;  vb = *(const uint4*)(vs + 64);
    }

    for (int t = 0; t < npair; ++t) {
      const int pb = (t & 1) * 2;    // buffer pair base {pb, pb+1}
      *(uint4*)&Ks[pb][srow*LDQ + sco]   = ka;
      *(uint4*)&Ks[pb+1][srow*LDQ + sco] = kb;
      {   // V stores: swap 8B halves on odd 8-row stripes (bank-conflict fix)
        uint4 vaS = vsw ? make_uint4(va.z, va.w, va.x, va.y) : va;
        uint4 vbS = vsw ? make_uint4(vb.z, vb.w, vb.x, vb.y) : vb;
        *(uint4*)&Vs[pb][srow*LDQ + sco]   = vaS;
        *(uint4*)&Vs[pb+1][srow*LDQ + sco] = vbS;
      }
      if (t + 1 < npair) {   // prefetch next pair (tiles 2t+2, 2t+3)
        const unsigned short* ks = kbase + (size_t)((2*t+2)*64 + srow)*HD + sco;
        ka = *(const uint4*)ks;  kb = *(const uint4*)(ks + 64*HD);
        const unsigned short* vs = vbase + (size_t)srow*SEQ + (2*t+2)*64 + sco;
        va = *(const uint4*)vs;  vb = *(const uint4*)(vs + 64);
      }
      __syncthreads();   // ONE barrier per pair (2 tiles)

      #pragma unroll
      for (int half = 0; half < 2; ++half) {
        const int bb = pb + half;
        const int sbase = (2*t + half) * 64;
        if (sbase > qwbase + 15) continue;   // wave fully masked for this tile
        // scores: S^T = K * Q^T (K=32)
        f32x4 sc[4];
        __builtin_amdgcn_s_setprio(1);
        #pragma unroll
        for (int sf = 0; sf < 4; sf++) {
          bf16x8 a0 = *(const bf16x8*)&Ks[bb][(sf*16 + lrow)*LDQ + quad*8];
          bf16x8 a1 = *(const bf16x8*)&Ks[bb][(sf*16 + lrow)*LDQ + 32 + quad*8];
          f32x4 z = (f32x4){0.f,0.f,0.f,0.f};
          z = __builtin_amdgcn_mfma_f32_16x16x32_bf16(a0, qb0, z, 0, 0, 0);
          z = __builtin_amdgcn_mfma_f32_16x16x32_bf16(a1, qb1, z, 0, 0, 0);
          sc[sf] = z;
        }
        __builtin_amdgcn_s_setprio(0);
        if (sbase + 63 > qwbase) {   // element mask (diag-adjacent tiles only)
          int ql = qwbase + lrow;
          #pragma unroll
          for (int sf = 0; sf < 4; sf++)
            #pragma unroll
            for (int r = 0; r < 4; r++)
              if (sbase + sf*16 + quad*4 + r > ql) sc[sf][r] += MASK2;
        }
        // p = exp2(s); P lands directly in K=16 B-layout
        s16x4 pf[4];
        float lp = 0.f;
        #pragma unroll
        for (int sf = 0; sf < 4; sf++) {
          Pack4 pk;
          #pragma unroll
          for (int r = 0; r < 4; r++) {
            float pe = __builtin_amdgcn_exp2f(sc[sf][r]);
            lp += pe;
            pk.e[r] = __builtin_bit_cast(unsigned short, (__bf16)pe);
          }
          pf[sf] = __builtin_bit_cast(s16x4, pk.v);
        }
        ls += lp;
        // PV: O^T += V^T * P^T (K=16); reads use swizzled sub-offset vq
        __builtin_amdgcn_s_setprio(1);
        #pragma unroll
        for (int df = 0; df < 4; df++) {
          s16x4 v0 = *(const s16x4*)&Vs[bb][(df*16 + lrow)*LDQ +  0 + vq];
          s16x4 v1 = *(const s16x4*)&Vs[bb][(df*16 + lrow)*LDQ + 16 + vq];
          s16x4 v2 = *(const s16x4*)&Vs[bb][(df*16 + lrow)*LDQ + 32 + vq];
          s16x4 v3 = *(const s16x4*)&Vs[bb][(df*16 + lrow)*LDQ + 48 + vq];
          od[df] = __builtin_amdgcn_mfma_f32_16x16x16bf16_1k(v0, pf[0], od[df], 0, 0, 0);
          od[df] = __builtin_amdgcn_mfma_f32_16x16x16bf16_1k(v1, pf[1], od[df], 0, 0, 0);
          od[df] = __builtin_amdgcn_mfma_f32_16x16x16bf16_1k(v2, pf[2], od[df], 0, 0, 0);
          od[df] = __builtin_amdgcn_mfma_f32_16x16x16bf16_1k(v3, pf[3], od[df], 0, 0, 0);
        }
        __builtin_amdgcn_s_setprio(0);
      } // half
    } // t

    // reduce l across quads (q id depends only on lane&15)
    ls += __shfl_xor(ls, 16);
    ls += __shfl_xor(ls, 32);

    __syncthreads();   // all Ks/Vs readers done; QC (=Vs[0..1]) is free
    {
      float f = ((rep < 2) ? SCL2F : 1.0f) / ls;
      #pragma unroll
      for (int df = 0; df < 4; df++) {
        Pack4 pk;
        #pragma unroll
        for (int r = 0; r < 4; r++)
          pk.e[r] = __builtin_bit_cast(unsigned short, (__bf16)(od[df][r] * f));
        *(us4*)&QC[(w*16 + lrow)*LDQ + df*16 + quad*4] = pk.v;
      }
    }
    __syncthreads();
    if (rep < 2) {   // reload chained Q frags
      qb0 = *(const bf16x8*)&QC[(w*16 + lrow)*LDQ + quad*8];
      qb1 = *(const bf16x8*)&QC[(w*16 + lrow)*LDQ + 32 + quad*8];
      __syncthreads();   // reloads done before next rep's stores to Vs
    }
  } // rep

  {   // coalesced ctx store from QC
    unsigned short* dst = cbase + (size_t)(qt*128 + qrow)*HD + qc0;
    *(uint4*)dst       = *(const uint4*)&QC[qrow*LDQ + qc0];
    *(uint4*)(dst + 8) = *(const uint4*)&QC[qrow*LDQ + qc0 + 8];
  }
}

// ---------------- out projection: 128x64x64 tiles, async staging, swizzled -------
__global__ __launch_bounds__(256) void out_gemm(
    const unsigned short* __restrict__ ctx, const unsigned short* __restrict__ owb,
    const float* __restrict__ bias, float* __restrict__ out)
{
  __shared__ __align__(16) unsigned short As[128*64];
  __shared__ __align__(16) unsigned short Bs[64*64];
  const int tid = threadIdx.x;
  const int m0 = blockIdx.y * 128, n0 = blockIdx.x * 64;
  const int wave = tid >> 6, lane = tid & 63;
  const int wm = (wave >> 1) * 64, wn = (wave & 1) * 32;
  const int lrow = lane & 15, quad = lane >> 4;

  const int dr = lane >> 3, pg = lane & 7;
  const int sg = (pg ^ dr) * 8;
  size_t aoff[4]; unsigned short* lA[4];
  #pragma unroll
  for (int i = 0; i < 4; i++) {
    int c = wave*4 + i;
    int row = m0 + c*8 + dr;
    aoff[i] = ((size_t)((row >> 11)*NHEADS)*SEQ + (row & 2047))*HD + sg;
    lA[i] = &As[c*512];
  }
  const unsigned short* gB[2]; unsigned short* lB[2];
  #pragma unroll
  for (int j = 0; j < 2; j++) {
    int c = wave*2 + j;
    gB[j] = owb + (size_t)(n0 + c*8 + dr) * D_MODEL + sg;
    lB[j] = &Bs[c*512];
  }
  const int px0 = (quad ^ (lrow & 7)) * 8;
  const int px1 = ((quad + 4) ^ (lrow & 7)) * 8;

  f32x4 acc[4][2];
  #pragma unroll
  for (int i = 0; i < 4; i++)
    #pragma unroll
    for (int j = 0; j < 2; j++) acc[i][j] = (f32x4){0.f,0.f,0.f,0.f};

  for (int k0 = 0; k0 < D_MODEL; k0 += 64) {
    size_t hoff = (size_t)(k0 >> 6) * SEQ * HD;
    __syncthreads();
    #pragma unroll
    for (int i = 0; i < 4; i++) gl_lds16(ctx + aoff[i] + hoff, lA[i]);
    #pragma unroll
    for (int j = 0; j < 2; j++) gl_lds16(gB[j] + k0, lB[j]);
    __syncthreads();
    bf16x8 af[4][2], bfr[2][2];
    #pragma unroll
    for (int mf = 0; mf < 4; mf++) {
      int row = wm + mf*16 + lrow;
      af[mf][0] = *(const bf16x8*)&As[row*64 + px0];
      af[mf][1] = *(const bf16x8*)&As[row*64 + px1];
    }
    #pragma unroll
    for (int nb = 0; nb < 2; nb++) {
      int row = wn + nb*16 + lrow;
      bfr[nb][0] = *(const bf16x8*)&Bs[row*64 + px0];
      bfr[nb][1] = *(const bf16x8*)&Bs[row*64 + px1];
    }
    #pragma unroll
    for (int h = 0; h < 2; h++)
      #pragma unroll
      for (int mf = 0; mf < 4; mf++)
        #pragma unroll
        for (int nb = 0; nb < 2; nb++)
          acc[mf][nb] = __builtin_amdgcn_mfma_f32_16x16x32_bf16(af[mf][h], bfr[nb][h], acc[mf][nb], 0, 0, 0);
  }

  #pragma unroll
  for (int mf = 0; mf < 4; mf++) {
    #pragma unroll
    for (int nb = 0; nb < 2; nb++) {
      #pragma unroll
      for (int r = 0; r < 4; r++) {
        int mm = m0 + wm + mf*16 + quad*4 + r;
        int n  = n0 + wn + nb*16 + lrow;
        out[(size_t)mm * D_MODEL + n] = acc[mf][nb][r] + bias[n];
      }
    }
  }
}

extern "C" void kernel_launch(void* const* d_in, const int* in_sizes, int n_in,
                              void* d_out, int out_size, void* d_ws, size_t ws_size,
                              hipStream_t stream) {
  (void)in_sizes; (void)n_in; (void)out_size; (void)ws_size;
  const float* x      = (const float*)d_in[0];
  const float* Wqkv_w = (const float*)d_in[1];
  const float* Wqkv_b = (const float*)d_in[2];
  const float* out_w  = (const float*)d_in[3];
  const float* out_b  = (const float*)d_in[4];
  float* out = (float*)d_out;

  unsigned short* ws = (unsigned short*)d_ws;
  unsigned short* xb  = ws;                              // 4.19M elems; reused as ctx
  unsigned short* wqb = ws + CVT_N1;                     // 3.15M
  unsigned short* owb = ws + CVT_N1 + CVT_N2;            // 1.05M
  unsigned short* q   = ws + CVT_N1 + CVT_N2 + CVT_N3;   // 4.19M each
  unsigned short* k   = q + (size_t)NROWS*D_MODEL;
  unsigned short* vT  = k + (size_t)NROWS*D_MODEL;       // [bh][d][s] transposed
  unsigned short* ctx = xb;                              // alias: xb dead after qkv

  cvt_all<<<(CVT_N1+CVT_N2+CVT_N3)/(256*8), 256, 0, stream>>>(x, Wqkv_w, out_w, xb, wqb, owb);
  qkv_gemm<<<dim3(NQKV/128, NROWS/128), 256, 0, stream>>>(xb, wqb, Wqkv_b, q, k, vT);
  attn3<<<dim3(BATCH*NHEADS, SEQ/128), 512, 0, stream>>>(q, k, vT, ctx);
  out_gemm<<<dim3(D_MODEL/64, NROWS/128), 256, 0, stream>>>(ctx, owb, out_b, out);
}